// Round 2
// baseline (300.516 us; speedup 1.0000x reference)
//
#include <hip/hip_runtime.h>

// Problem constants (from reference setup_inputs)
constexpr int NN = 50000;   // nodes
constexpr int H  = 128;     // hidden
constexpr int F  = 256;     // input features
constexpr int C  = 40;      // classes

// graph-prepass partitioning: 8 ranges of 6400 nodes, 32 chunks, 1024-thread
// hist/fill blocks. hist linear ids 0..255: id%8 = range => XCD pinning.
constexpr int RSZ = 6400;
constexpr int NRG = 8;
constexpr int CHP = 32;     // partial chunks (merge chain length)
constexpr int GBK = (NN + 63) / 64;   // 782 GEMM row-blocks

typedef short bf16x8 __attribute__((ext_vector_type(8)));
typedef float f32x4  __attribute__((ext_vector_type(4)));

__device__ inline unsigned short f2bf(float f) {          // RNE fp32 -> bf16
    unsigned u = __float_as_uint(f);
    u += 0x7fff + ((u >> 16) & 1);
    return (unsigned short)(u >> 16);
}
__device__ inline float bf2f(unsigned short s) {
    return __uint_as_float(((unsigned)s) << 16);
}

// async global->LDS DMA, 16B per lane. LDS dest = wave-uniform base + lane*16
// (we pass per-lane base+lane*16; lane0's value is the wave base -> consistent).
__device__ __forceinline__ void gll16(const unsigned short* g, void* l) {
    __builtin_amdgcn_global_load_lds(
        (const __attribute__((address_space(1))) void*)g,
        (__attribute__((address_space(3))) void*)l, 16, 0, 0);
}

// ------------------------------------------------ GEMM body (shared device fn)
// All inputs PRE-SPLIT bf16 hi/lo planes in DMA-friendly layout:
//   A plane chunk(rb,t,k4,row) = ((rb*NK+t)*4+k4)*64+row, 8 bf16 each (row=0..63)
//   B plane chunk(t,k4,col)    = (t*4+k4)*BN+col
// K-loop: global_load_lds next tile -> ds_read_b128 frags -> 24 MFMA -> barrier.
// MODE 0: outf[gr*Nout+gc] = acc + bias (gc<Nout), fp32 (classifier)
// MODE 1: oh = row-major bf16(acc*row_scale)  (feeds aggregate)
// MODE 2: oh/ol = hi/lo split of (acc + bias) in A-plane layout keyed NK'=4
template<int MODE, int BN, int NK>
__device__ __forceinline__ void gemm_body(
        int by,
        const unsigned short* __restrict__ Ah, const unsigned short* __restrict__ Al,
        const unsigned short* __restrict__ Bh, const unsigned short* __restrict__ Bl,
        const float* __restrict__ bias, const float* __restrict__ row_scale,
        float* __restrict__ outf, unsigned short* __restrict__ oh,
        unsigned short* __restrict__ ol, int M, int Nout) {
    constexpr int NT  = BN / 64;
    constexpr int BCH = 4 * BN;                 // B chunks per K-step
    __shared__ uint4 sAh[2][256], sAl[2][256];
    __shared__ uint4 sBh[2][BCH], sBl[2][BCH];

    const int tid  = threadIdx.x;
    const int wave = tid >> 6;
    const int lane = tid & 63;
    const int quad = lane >> 4;
    const int lr   = lane & 15;
    const int row0 = by * 64;
    const int wn0  = wave * (BN / 4);

    f32x4 acc[4][NT];
#pragma unroll
    for (int mt = 0; mt < 4; mt++)
#pragma unroll
        for (int nt = 0; nt < NT; nt++)
            acc[mt][nt] = (f32x4){0.f, 0.f, 0.f, 0.f};

    const unsigned short* aH = Ah + ((long)by * NK) * 2048;
    const unsigned short* aL = Al + ((long)by * NK) * 2048;

    auto stage = [&](int t, int b) {
        gll16(aH + (long)t * 2048 + tid * 8, &sAh[b][tid]);
        gll16(aL + (long)t * 2048 + tid * 8, &sAl[b][tid]);
        const unsigned short* bH = Bh + (long)t * BCH * 8;
        const unsigned short* bL = Bl + (long)t * BCH * 8;
#pragma unroll
        for (int r = 0; r < BCH / 256; r++) {
            int c = tid + r * 256;
            gll16(bH + c * 8, &sBh[b][c]);
            gll16(bL + c * 8, &sBl[b][c]);
        }
    };

    stage(0, 0);
    __syncthreads();                            // vmcnt(0) drain: tile 0 ready
    int cur = 0;
    for (int t = 0; t < NK; t++) {
        if (t + 1 < NK) stage(t + 1, cur ^ 1);  // in-flight during MFMA below
        bf16x8 ah[4], av[4], bh[NT], bv[NT];
#pragma unroll
        for (int mt = 0; mt < 4; mt++) {
            ah[mt] = *(const bf16x8*)&sAh[cur][quad * 64 + mt * 16 + lr];
            av[mt] = *(const bf16x8*)&sAl[cur][quad * 64 + mt * 16 + lr];
        }
#pragma unroll
        for (int nt = 0; nt < NT; nt++) {
            bh[nt] = *(const bf16x8*)&sBh[cur][quad * BN + wn0 + nt * 16 + lr];
            bv[nt] = *(const bf16x8*)&sBl[cur][quad * BN + wn0 + nt * 16 + lr];
        }
#pragma unroll
        for (int mt = 0; mt < 4; mt++)
#pragma unroll
            for (int nt = 0; nt < NT; nt++) {
                acc[mt][nt] = __builtin_amdgcn_mfma_f32_16x16x32_bf16(ah[mt], bh[nt], acc[mt][nt], 0, 0, 0);
                acc[mt][nt] = __builtin_amdgcn_mfma_f32_16x16x32_bf16(av[mt], bh[nt], acc[mt][nt], 0, 0, 0);
                acc[mt][nt] = __builtin_amdgcn_mfma_f32_16x16x32_bf16(ah[mt], bv[nt], acc[mt][nt], 0, 0, 0);
            }
        __syncthreads();                        // drains stage(t+1) + retires reads
        cur ^= 1;
    }

#pragma unroll
    for (int mt = 0; mt < 4; mt++) {
#pragma unroll
        for (int nt = 0; nt < NT; nt++) {
            const int gc = wn0 + nt * 16 + lr;
#pragma unroll
            for (int r = 0; r < 4; r++) {
                const int gr = row0 + mt * 16 + quad * 4 + r;
                float v = acc[mt][nt][r];
                if (MODE == 0) {
                    if (gr < M && gc < Nout) outf[(long)gr * Nout + gc] = v + bias[gc];
                } else if (MODE == 1) {
                    if (gr < M) oh[(long)gr * 128 + gc] = f2bf(v * row_scale[gr]);
                } else {
                    float x = v + bias[gc];     // pad rows: A-planes are zeroed -> x=bias, harmless
                    unsigned short hh = f2bf(x);
                    unsigned short ll = f2bf(x - bf2f(hh));
                    long idx = ((((long)by * 4 + (gc >> 5)) * 4 + ((gc >> 3) & 3)) * 64
                                + (mt * 16 + quad * 4 + r)) * 8 + (gc & 7);
                    oh[idx] = hh;
                    ol[idx] = ll;
                }
            }
        }
    }
}

// ------------------------------------------------ D1: hist (256) + wprep (72) + A-split (782)
// 1024 threads. Partials chunk-major u16. A-split: n_feats fp32 -> hi/lo bf16
// planes in the GEMM DMA layout (transpose-through-LDS, coalesced both sides).
__global__ __launch_bounds__(1024) void hist_prep(
        const int* __restrict__ src, const int* __restrict__ dst,
        unsigned short* __restrict__ p_out, unsigned short* __restrict__ p_in, int E,
        const float* __restrict__ Wp, const float* __restrict__ W1,
        const float* __restrict__ W2, const float* __restrict__ Wc,
        unsigned short* __restrict__ ph, unsigned short* __restrict__ pl,
        unsigned short* __restrict__ h1h, unsigned short* __restrict__ h1l,
        unsigned short* __restrict__ h2h, unsigned short* __restrict__ h2l,
        unsigned short* __restrict__ chh, unsigned short* __restrict__ cll,
        const float* __restrict__ nf,
        unsigned short* __restrict__ nfh, unsigned short* __restrict__ nfl) {
    __shared__ int ho[RSZ];
    __shared__ int hd[RSZ];
    const int t = threadIdx.x;
    if (blockIdx.x < NRG * CHP) {
        const int r = blockIdx.x & 7;        // linear id = r + 8*b (XCD pinning)
        const int b = blockIdx.x >> 3;
        for (int i = t; i < RSZ; i += 1024) { ho[i] = 0; hd[i] = 0; }
        __syncthreads();
        const int base = r * RSZ;
        const int CE = (E + CHP - 1) / CHP;
        const int e0 = b * CE, e1 = min(E, e0 + CE);
#pragma unroll 4
        for (int e = e0 + t; e < e1; e += 1024) {
            int s = src[e], d = dst[e];
            unsigned so = (unsigned)(s - base);
            unsigned dof = (unsigned)(d - base);
            if (so < (unsigned)RSZ) atomicAdd(&ho[so], 1);
            if (dof < (unsigned)RSZ) atomicAdd(&hd[dof], 1);
        }
        __syncthreads();
        const long po = ((long)r * CHP + b) * RSZ;   // even
        unsigned* o32 = (unsigned*)&p_out[po];
        unsigned* i32 = (unsigned*)&p_in[po];
        for (int i = t; i < RSZ / 2; i += 1024) {
            o32[i] = (unsigned)ho[2 * i] | ((unsigned)ho[2 * i + 1] << 16);
            i32[i] = (unsigned)hd[2 * i] | ((unsigned)hd[2 * i + 1] << 16);
        }
        return;
    }
    if (blockIdx.x < NRG * CHP + 72) {
        // weight transpose + hi/lo split -> DMA layout (73728 = 72*1024 elems)
        int i = (blockIdx.x - NRG * CHP) * 1024 + t;
        const float* W; unsigned short *Bh, *Bl; int K, N, Np, j;
        if (i < 32768)        { W = Wp; Bh = ph;  Bl = pl;  K = 256; N = 128; Np = 128; j = i; }
        else if (i < 49152)   { W = W1; Bh = h1h; Bl = h1l; K = 128; N = 128; Np = 128; j = i - 32768; }
        else if (i < 65536)   { W = W2; Bh = h2h; Bl = h2l; K = 128; N = 128; Np = 128; j = i - 49152; }
        else if (i < 73728)   { W = Wc; Bh = chh; Bl = cll; K = 128; N = 40;  Np = 64;  j = i - 65536; }
        else return;
        int n = j / K, k = j % K;
        float v = (n < N) ? W[(long)k * N + n] : 0.f;
        unsigned short hh = f2bf(v);
        unsigned short ll = f2bf(v - bf2f(hh));
        long di = (((long)(k >> 5) * 4 + ((k >> 3) & 3)) * Np + n) * 8 + (k & 7);
        Bh[di] = hh;
        Bl[di] = ll;
        return;
    }
    // ---- A-split: rb-th 64-row block of n_feats -> nfh/nfl planes (NK=8)
    const int rb = blockIdx.x - (NRG * CHP + 72);
    float* at = (float*)ho;                  // 64 x 33 fp32 (8.4KB, aliases hist LDS)
    for (int tt = 0; tt < 8; tt++) {
        if (t < 512) {                       // coalesced load of 64x32 subtile
            int row = t >> 3, cq = t & 7;
            int grow = rb * 64 + row;
            float4 v = make_float4(0.f, 0.f, 0.f, 0.f);
            if (grow < NN) v = *(const float4*)&nf[(long)grow * F + tt * 32 + cq * 4];
            at[row * 33 + cq * 4 + 0] = v.x;
            at[row * 33 + cq * 4 + 1] = v.y;
            at[row * 33 + cq * 4 + 2] = v.z;
            at[row * 33 + cq * 4 + 3] = v.w;
        }
        __syncthreads();
        if (t < 512) {                       // split + coalesced 8B stores
            int k4 = t >> 7, rw = (t >> 1) & 63, hf = t & 1;
            float x0 = at[rw * 33 + k4 * 8 + hf * 4 + 0];
            float x1 = at[rw * 33 + k4 * 8 + hf * 4 + 1];
            float x2 = at[rw * 33 + k4 * 8 + hf * 4 + 2];
            float x3 = at[rw * 33 + k4 * 8 + hf * 4 + 3];
            unsigned short h0 = f2bf(x0), h1 = f2bf(x1), h2 = f2bf(x2), h3 = f2bf(x3);
            unsigned short l0 = f2bf(x0 - bf2f(h0));
            unsigned short l1 = f2bf(x1 - bf2f(h1));
            unsigned short l2 = f2bf(x2 - bf2f(h2));
            unsigned short l3 = f2bf(x3 - bf2f(h3));
            long base = ((((long)rb * 8 + tt) * 4 + k4) * 64 + rw) * 8 + hf * 4;
            *(ushort4*)&nfh[base] = make_ushort4(h0, h1, h2, h3);
            *(ushort4*)&nfl[base] = make_ushort4(l0, l1, l2, l3);
        }
        __syncthreads();
    }
}

// ------------------------------------------------ D2: merge_scan (196) + proj GEMM (782)
__global__ __launch_bounds__(256) void merge_proj(
        const unsigned short* __restrict__ p_out, unsigned short* __restrict__ p_in,
        int* __restrict__ cnt_in, float* __restrict__ rs_out, float* __restrict__ rs_in,
        int* __restrict__ row_start, int* __restrict__ block_sums, int n, int nb,
        const unsigned short* __restrict__ Ah, const unsigned short* __restrict__ Al,
        const unsigned short* __restrict__ Bh, const unsigned short* __restrict__ Bl,
        const float* __restrict__ bias,
        unsigned short* __restrict__ xh, unsigned short* __restrict__ xl, int M) {
    if ((int)blockIdx.x < nb) {
        __shared__ int sh[256];
        const int t = threadIdx.x;
        const int i = blockIdx.x * 256 + t;
        int si = 0;
        if (i < n) {
            const int r = i / RSZ, off = i % RSZ;
            const long pb = (long)r * CHP * RSZ + off;
            int so = 0;
#pragma unroll 8
            for (int b = 0; b < CHP; b++) {
                so += p_out[pb + (long)b * RSZ];
                int v = p_in[pb + (long)b * RSZ];
                p_in[pb + (long)b * RSZ] = (unsigned short)si;
                si += v;
            }
            cnt_in[i] = si;
            rs_out[i] = rsqrtf((float)max(so, 1));
            rs_in[i]  = rsqrtf((float)max(si, 1));
        }
        sh[t] = si;
        __syncthreads();
#pragma unroll
        for (int off = 1; off < 256; off <<= 1) {
            int u = (t >= off) ? sh[t - off] : 0;
            __syncthreads();
            sh[t] += u;
            __syncthreads();
        }
        if (i < n) row_start[i] = sh[t] - si;
        if (t == 255) block_sums[blockIdx.x] = sh[255];
        return;
    }
    gemm_body<2, 128, 8>(blockIdx.x - nb, Ah, Al, Bh, Bl, bias, nullptr,
                         nullptr, xh, xl, M, 128);
}

// ------------------------------------------------ D3: scan_sums (1) + layer1 GEMM (782)
__global__ __launch_bounds__(256) void scansums_gemm(
        int* __restrict__ block_sums, int nb,
        const unsigned short* __restrict__ Ah, const unsigned short* __restrict__ Al,
        const unsigned short* __restrict__ Bh, const unsigned short* __restrict__ Bl,
        const float* __restrict__ row_scale, unsigned short* __restrict__ outh, int M) {
    if (blockIdx.x == 0) {
        __shared__ int sh[256];
        const int t = threadIdx.x;
        const int v = (t < nb) ? block_sums[t] : 0;
        sh[t] = v;
        __syncthreads();
#pragma unroll
        for (int off = 1; off < 256; off <<= 1) {
            int u = (t >= off) ? sh[t - off] : 0;
            __syncthreads();
            sh[t] += u;
            __syncthreads();
        }
        if (t < nb) block_sums[t] = sh[t] - v;
        return;
    }
    gemm_body<1, 128, 4>(blockIdx.x - 1, Ah, Al, Bh, Bl, nullptr, row_scale,
                         nullptr, outh, nullptr, M, 128);
}

// ------------------------------------------------ standalone GEMM wrapper
template<int MODE, int BN, int NK>
__global__ __launch_bounds__(256) void gemm_std(
        const unsigned short* __restrict__ Ah, const unsigned short* __restrict__ Al,
        const unsigned short* __restrict__ Bh, const unsigned short* __restrict__ Bl,
        const float* __restrict__ bias, const float* __restrict__ row_scale,
        float* __restrict__ outf, unsigned short* __restrict__ oh,
        unsigned short* __restrict__ ol, int M, int Nout) {
    gemm_body<MODE, BN, NK>(blockIdx.x, Ah, Al, Bh, Bl, bias, row_scale,
                            outf, oh, ol, M, Nout);
}

// ------------------------------------------------ D4: CSR fill, 1024 threads
__global__ __launch_bounds__(1024) void fill_csr_part(
        const int* __restrict__ src, const int* __restrict__ dst,
        const int* __restrict__ row_start, const int* __restrict__ block_sums,
        const unsigned short* __restrict__ p_in,
        int* __restrict__ csr_src, int E, int n_nodes) {
    __shared__ int cur[RSZ];
    const int r = blockIdx.x;
    const int b = blockIdx.y;
    const int base = r * RSZ;
    const long po = ((long)r * CHP + b) * RSZ;
    for (int i = threadIdx.x; i < RSZ; i += 1024) {
        int node = base + i;
        int rs = (node < n_nodes) ? (row_start[node] + block_sums[node >> 8]) : 0;
        cur[i] = rs + (int)p_in[po + i];
    }
    __syncthreads();
    const int CE = (E + CHP - 1) / CHP;
    const int e0 = b * CE, e1 = min(E, e0 + CE);
#pragma unroll 8
    for (int e = e0 + threadIdx.x; e < e1; e += 1024) {
        int d = dst[e];
        unsigned dof = (unsigned)(d - base);
        if (dof < (unsigned)RSZ) {
            int pos = atomicAdd(&cur[dof], 1);   // LDS atomic
            csr_src[pos] = src[e];
        }
    }
}

// ---------------------------------------------------------------- aggregation (bf16 h)
// out: hi/lo split planes in the GEMM A layout (NK'=4) -> next GEMM DMA-stages it.
__global__ __launch_bounds__(256) void aggregate_bf16(
        const uint4* __restrict__ h4, const int* __restrict__ csr_src,
        const int* __restrict__ row_start, const int* __restrict__ block_sums,
        const int* __restrict__ cnt_in,
        const float* __restrict__ rs_in, const float* __restrict__ bias,
        unsigned short* __restrict__ oh, unsigned short* __restrict__ ol, int nodes) {
    const int wave = threadIdx.x >> 6;
    const int lane = threadIdx.x & 63;
    const int grp  = lane >> 4;        // 0..3 = neighbor slot
    const int sl   = lane & 15;        // uint4 index in row
    const int v = blockIdx.x * 4 + wave;
    if (v >= nodes) return;
    const int s0  = row_start[v] + block_sums[v >> 8];
    const int cnt = cnt_in[v];

    float ax0 = 0.f, ay0 = 0.f, ax1 = 0.f, ay1 = 0.f;
    float ax2 = 0.f, ay2 = 0.f, ax3 = 0.f, ay3 = 0.f;
    int i0 = 0;
    for (; i0 + 8 <= cnt; i0 += 8) {               // 8 neighbors in flight
        int sA = csr_src[s0 + i0 + grp];
        int sB = csr_src[s0 + i0 + 4 + grp];
        uint4 uA = h4[(long)sA * 16 + sl];
        uint4 uB = h4[(long)sB * 16 + sl];
        ax0 += __uint_as_float(uA.x << 16) + __uint_as_float(uB.x << 16);
        ay0 += __uint_as_float(uA.x & 0xffff0000u) + __uint_as_float(uB.x & 0xffff0000u);
        ax1 += __uint_as_float(uA.y << 16) + __uint_as_float(uB.y << 16);
        ay1 += __uint_as_float(uA.y & 0xffff0000u) + __uint_as_float(uB.y & 0xffff0000u);
        ax2 += __uint_as_float(uA.z << 16) + __uint_as_float(uB.z << 16);
        ay2 += __uint_as_float(uA.z & 0xffff0000u) + __uint_as_float(uB.z & 0xffff0000u);
        ax3 += __uint_as_float(uA.w << 16) + __uint_as_float(uB.w << 16);
        ay3 += __uint_as_float(uA.w & 0xffff0000u) + __uint_as_float(uB.w & 0xffff0000u);
    }
    for (; i0 + 4 <= cnt; i0 += 4) {
        int s = csr_src[s0 + i0 + grp];
        uint4 u = h4[(long)s * 16 + sl];
        ax0 += __uint_as_float(u.x << 16); ay0 += __uint_as_float(u.x & 0xffff0000u);
        ax1 += __uint_as_float(u.y << 16); ay1 += __uint_as_float(u.y & 0xffff0000u);
        ax2 += __uint_as_float(u.z << 16); ay2 += __uint_as_float(u.z & 0xffff0000u);
        ax3 += __uint_as_float(u.w << 16); ay3 += __uint_as_float(u.w & 0xffff0000u);
    }
    if (i0 + grp < cnt) {                          // 0..3 tail neighbors
        int s = csr_src[s0 + i0 + grp];
        uint4 u = h4[(long)s * 16 + sl];
        ax0 += __uint_as_float(u.x << 16); ay0 += __uint_as_float(u.x & 0xffff0000u);
        ax1 += __uint_as_float(u.y << 16); ay1 += __uint_as_float(u.y & 0xffff0000u);
        ax2 += __uint_as_float(u.z << 16); ay2 += __uint_as_float(u.z & 0xffff0000u);
        ax3 += __uint_as_float(u.w << 16); ay3 += __uint_as_float(u.w & 0xffff0000u);
    }
    // sum across the 4 lane-groups (bits 4,5 of lane)
    ax0 += __shfl_xor(ax0, 16); ay0 += __shfl_xor(ay0, 16);
    ax1 += __shfl_xor(ax1, 16); ay1 += __shfl_xor(ay1, 16);
    ax2 += __shfl_xor(ax2, 16); ay2 += __shfl_xor(ay2, 16);
    ax3 += __shfl_xor(ax3, 16); ay3 += __shfl_xor(ay3, 16);
    ax0 += __shfl_xor(ax0, 32); ay0 += __shfl_xor(ay0, 32);
    ax1 += __shfl_xor(ax1, 32); ay1 += __shfl_xor(ay1, 32);
    ax2 += __shfl_xor(ax2, 32); ay2 += __shfl_xor(ay2, 32);
    ax3 += __shfl_xor(ax3, 32); ay3 += __shfl_xor(ay3, 32);

    if (grp == 0) {                                // lanes 0..15: cols sl*8..sl*8+7
        const float rs = rs_in[v];
        const float2 b0 = ((const float2*)bias)[sl * 4 + 0];
        const float2 b1 = ((const float2*)bias)[sl * 4 + 1];
        const float2 b2 = ((const float2*)bias)[sl * 4 + 2];
        const float2 b3 = ((const float2*)bias)[sl * 4 + 3];
        float w0 = fmaxf(ax0 * rs + b0.x, 0.f), w1 = fmaxf(ay0 * rs + b0.y, 0.f);
        float w2 = fmaxf(ax1 * rs + b1.x, 0.f), w3 = fmaxf(ay1 * rs + b1.y, 0.f);
        float w4 = fmaxf(ax2 * rs + b2.x, 0.f), w5 = fmaxf(ay2 * rs + b2.y, 0.f);
        float w6 = fmaxf(ax3 * rs + b3.x, 0.f), w7 = fmaxf(ay3 * rs + b3.y, 0.f);
        unsigned short h0 = f2bf(w0), h1 = f2bf(w1), h2 = f2bf(w2), h3 = f2bf(w3);
        unsigned short h4v = f2bf(w4), h5 = f2bf(w5), h6 = f2bf(w6), h7 = f2bf(w7);
        uint4 hv, lv;
        hv.x = (unsigned)h0 | ((unsigned)h1 << 16);
        hv.y = (unsigned)h2 | ((unsigned)h3 << 16);
        hv.z = (unsigned)h4v | ((unsigned)h5 << 16);
        hv.w = (unsigned)h6 | ((unsigned)h7 << 16);
        unsigned short l0 = f2bf(w0 - bf2f(h0)), l1 = f2bf(w1 - bf2f(h1));
        unsigned short l2 = f2bf(w2 - bf2f(h2)), l3 = f2bf(w3 - bf2f(h3));
        unsigned short l4 = f2bf(w4 - bf2f(h4v)), l5 = f2bf(w5 - bf2f(h5));
        unsigned short l6 = f2bf(w6 - bf2f(h6)), l7 = f2bf(w7 - bf2f(h7));
        lv.x = (unsigned)l0 | ((unsigned)l1 << 16);
        lv.y = (unsigned)l2 | ((unsigned)l3 << 16);
        lv.z = (unsigned)l4 | ((unsigned)l5 << 16);
        lv.w = (unsigned)l6 | ((unsigned)l7 << 16);
        long chunk = (((long)(v >> 6) * 4 + (sl >> 2)) * 4 + (sl & 3)) * 64 + (v & 63);
        *(uint4*)&oh[chunk * 8] = hv;
        *(uint4*)&ol[chunk * 8] = lv;
    }
}

// ---------------------------------------------------------------- launch
extern "C" void kernel_launch(void* const* d_in, const int* in_sizes, int n_in,
                              void* d_out, int out_size, void* d_ws, size_t ws_size,
                              hipStream_t stream) {
    const float* n_feats = (const float*)d_in[0];
    const int*   src     = (const int*)d_in[1];
    const int*   dst     = (const int*)d_in[2];
    const float* Wp      = (const float*)d_in[3];
    const float* bp      = (const float*)d_in[4];
    const float* W1      = (const float*)d_in[5];
    const float* b1      = (const float*)d_in[6];
    const float* W2      = (const float*)d_in[7];
    const float* b2      = (const float*)d_in[8];
    const float* Wc      = (const float*)d_in[9];
    const float* bc      = (const float*)d_in[10];
    float* out = (float*)d_out;
    const int E = in_sizes[1];

    const long PSZ = (long)NRG * CHP * RSZ;    // partials: 1,638,400 u16 (3.28 MB)
    const long XPL = (long)GBK * 4 * 2048;     // x-plane elems (K=128 layout)
    const long NPL = (long)GBK * 8 * 2048;     // n_feats-plane elems (K=256 layout)

    // workspace layout (~101 MB of 256 MiB)
    char* ws = (char*)d_ws;
    unsigned short* hbuf  = (unsigned short*)ws;                    // NN*H bf16
    unsigned short* xh    = hbuf + (long)NN * H;                    // XPL
    unsigned short* xl    = xh + XPL;
    unsigned short* nfh   = xl + XPL;                               // NPL
    unsigned short* nfl   = nfh + NPL;
    unsigned short* bt_ph = nfl + NPL;                              // 8*4*128*8
    unsigned short* bt_pl = bt_ph + 32768;
    unsigned short* bt_1h = bt_pl + 32768;                          // 4*4*128*8
    unsigned short* bt_1l = bt_1h + 16384;
    unsigned short* bt_2h = bt_1l + 16384;
    unsigned short* bt_2l = bt_2h + 16384;
    unsigned short* bt_ch = bt_2l + 16384;                          // 4*4*64*8
    unsigned short* bt_cl = bt_ch + 8192;
    int*   cnt_in     = (int*)(bt_cl + 8192);                       // N
    int*   row_start  = cnt_in + NN;                                // N (within-block excl)
    float* rs_out     = (float*)(row_start + NN);                   // N
    float* rs_in      = rs_out + NN;                                // N
    int*   block_sums = (int*)(rs_in + NN);                         // 256
    unsigned short* p_out = (unsigned short*)(block_sums + 256);    // PSZ u16
    unsigned short* p_in  = p_out + PSZ;                            // PSZ u16
    int*   csr_src    = (int*)(p_in + PSZ);                         // E

    const int NB = (NN + 255) / 256;    // 196

    // D1: histograms (256, XCD-pinned) + weight prep (72) + n_feats split (782)
    hist_prep<<<NRG * CHP + 72 + GBK, 1024, 0, stream>>>(
        src, dst, p_out, p_in, E, Wp, W1, W2, Wc,
        bt_ph, bt_pl, bt_1h, bt_1l, bt_2h, bt_2l, bt_ch, bt_cl,
        n_feats, nfh, nfl);
    // D2: merge+scan (196) + proj GEMM (782): xh/xl = split(n_feats @ Wp + bp)
    merge_proj<<<NB + GBK, 256, 0, stream>>>(
        p_out, p_in, cnt_in, rs_out, rs_in, row_start, block_sums, NN, NB,
        nfh, nfl, bt_ph, bt_pl, bp, xh, xl, NN);
    // D3: scan of block sums (1) + layer-1 GEMM (782): hbuf = bf16((x@W1)*rs_out)
    scansums_gemm<<<1 + GBK, 256, 0, stream>>>(
        block_sums, NB, xh, xl, bt_1h, bt_1l, rs_out, hbuf, NN);
    // D4: CSR fill (no global atomics), 1024 threads
    fill_csr_part<<<dim3(NRG, CHP), 1024, 0, stream>>>(
        src, dst, row_start, block_sums, p_in, csr_src, E, NN);
    // D5: aggregate 1 -> xh/xl = split(relu(rs_in * (A hbuf) + b1))
    aggregate_bf16<<<(NN + 3) / 4, 256, 0, stream>>>(
        (const uint4*)hbuf, csr_src, row_start, block_sums, cnt_in, rs_in, b1, xh, xl, NN);
    // D6: layer-2 GEMM: hbuf = bf16((x@W2)*rs_out)
    gemm_std<1, 128, 4><<<GBK, 256, 0, stream>>>(
        xh, xl, bt_2h, bt_2l, nullptr, rs_out, nullptr, hbuf, nullptr, NN, 128);
    // D7: aggregate 2 -> xh/xl
    aggregate_bf16<<<(NN + 3) / 4, 256, 0, stream>>>(
        (const uint4*)hbuf, csr_src, row_start, block_sums, cnt_in, rs_in, b2, xh, xl, NN);
    // D8: classifier: out = x @ Wc + bc (store-masked to 40 cols)
    gemm_std<0, 64, 4><<<GBK, 256, 0, stream>>>(
        xh, xl, bt_ch, bt_cl, bc, nullptr, out, nullptr, nullptr, NN, C);
}

// Round 3
// 292.046 us; speedup vs baseline: 1.0290x; 1.0290x over previous
//
#include <hip/hip_runtime.h>

// Problem constants (from reference setup_inputs)
constexpr int NN = 50000;   // nodes
constexpr int H  = 128;     // hidden
constexpr int F  = 256;     // input features
constexpr int C  = 40;      // classes

// graph-prepass partitioning: 8 ranges of 6400 nodes, 32 chunks, 1024-thread
// hist/fill blocks. hist linear ids 0..255: id%8 = range => XCD pinning.
constexpr int RSZ = 6400;
constexpr int NRG = 8;
constexpr int CHP = 32;     // partial chunks (merge chain length)
constexpr int GBK = (NN + 63) / 64;   // 782 GEMM row-blocks

typedef short bf16x8 __attribute__((ext_vector_type(8)));
typedef float f32x4  __attribute__((ext_vector_type(4)));

__device__ inline unsigned short f2bf(float f) {          // RNE fp32 -> bf16
    unsigned u = __float_as_uint(f);
    u += 0x7fff + ((u >> 16) & 1);
    return (unsigned short)(u >> 16);
}
__device__ inline float bf2f(unsigned short s) {
    return __uint_as_float(((unsigned)s) << 16);
}

// async global->LDS DMA, 16B per lane. LDS dest = wave-uniform base + lane*16
// (we pass per-lane base+lane*16; lane0's value is the wave base -> consistent).
__device__ __forceinline__ void gll16(const unsigned short* g, void* l) {
    __builtin_amdgcn_global_load_lds(
        (const __attribute__((address_space(1))) void*)g,
        (__attribute__((address_space(3))) void*)l, 16, 0, 0);
}

// ------------------------------------------------ GEMM body (shared device fn)
// All inputs PRE-SPLIT bf16 hi/lo planes in DMA-friendly layout:
//   A plane chunk(rb,t,k4,row) = ((rb*NK+t)*4+k4)*64+row, 8 bf16 each (row=0..63)
//   B plane chunk(t,k4,col)    = (t*4+k4)*BN+col
// K-loop: global_load_lds next tile -> ds_read_b128 frags -> 24 MFMA -> barrier.
// MODE 0: outf[gr*Nout+gc] = acc + bias (gc<Nout), fp32 (classifier)
// MODE 1: oh = row-major bf16(acc*row_scale)  (feeds aggregate)
// MODE 2: oh/ol = hi/lo split of (acc + bias) in A-plane layout keyed NK'=4
template<int MODE, int BN, int NK>
__device__ __forceinline__ void gemm_body(
        int by,
        const unsigned short* __restrict__ Ah, const unsigned short* __restrict__ Al,
        const unsigned short* __restrict__ Bh, const unsigned short* __restrict__ Bl,
        const float* __restrict__ bias, const float* __restrict__ row_scale,
        float* __restrict__ outf, unsigned short* __restrict__ oh,
        unsigned short* __restrict__ ol, int M, int Nout) {
    constexpr int NT  = BN / 64;
    constexpr int BCH = 4 * BN;                 // B chunks per K-step
    __shared__ uint4 sAh[2][256], sAl[2][256];
    __shared__ uint4 sBh[2][BCH], sBl[2][BCH];

    const int tid  = threadIdx.x;
    const int wave = tid >> 6;
    const int lane = tid & 63;
    const int quad = lane >> 4;
    const int lr   = lane & 15;
    const int row0 = by * 64;
    const int wn0  = wave * (BN / 4);

    f32x4 acc[4][NT];
#pragma unroll
    for (int mt = 0; mt < 4; mt++)
#pragma unroll
        for (int nt = 0; nt < NT; nt++)
            acc[mt][nt] = (f32x4){0.f, 0.f, 0.f, 0.f};

    const unsigned short* aH = Ah + ((long)by * NK) * 2048;
    const unsigned short* aL = Al + ((long)by * NK) * 2048;

    auto stage = [&](int t, int b) {
        gll16(aH + (long)t * 2048 + tid * 8, &sAh[b][tid]);
        gll16(aL + (long)t * 2048 + tid * 8, &sAl[b][tid]);
        const unsigned short* bH = Bh + (long)t * BCH * 8;
        const unsigned short* bL = Bl + (long)t * BCH * 8;
#pragma unroll
        for (int r = 0; r < BCH / 256; r++) {
            int c = tid + r * 256;
            gll16(bH + c * 8, &sBh[b][c]);
            gll16(bL + c * 8, &sBl[b][c]);
        }
    };

    stage(0, 0);
    __syncthreads();                            // vmcnt(0) drain: tile 0 ready
    int cur = 0;
    for (int t = 0; t < NK; t++) {
        if (t + 1 < NK) stage(t + 1, cur ^ 1);  // in-flight during MFMA below
        bf16x8 ah[4], av[4], bh[NT], bv[NT];
#pragma unroll
        for (int mt = 0; mt < 4; mt++) {
            ah[mt] = *(const bf16x8*)&sAh[cur][quad * 64 + mt * 16 + lr];
            av[mt] = *(const bf16x8*)&sAl[cur][quad * 64 + mt * 16 + lr];
        }
#pragma unroll
        for (int nt = 0; nt < NT; nt++) {
            bh[nt] = *(const bf16x8*)&sBh[cur][quad * BN + wn0 + nt * 16 + lr];
            bv[nt] = *(const bf16x8*)&sBl[cur][quad * BN + wn0 + nt * 16 + lr];
        }
#pragma unroll
        for (int mt = 0; mt < 4; mt++)
#pragma unroll
            for (int nt = 0; nt < NT; nt++) {
                acc[mt][nt] = __builtin_amdgcn_mfma_f32_16x16x32_bf16(ah[mt], bh[nt], acc[mt][nt], 0, 0, 0);
                acc[mt][nt] = __builtin_amdgcn_mfma_f32_16x16x32_bf16(av[mt], bh[nt], acc[mt][nt], 0, 0, 0);
                acc[mt][nt] = __builtin_amdgcn_mfma_f32_16x16x32_bf16(ah[mt], bv[nt], acc[mt][nt], 0, 0, 0);
            }
        __syncthreads();                        // drains stage(t+1) + retires reads
        cur ^= 1;
    }

#pragma unroll
    for (int mt = 0; mt < 4; mt++) {
#pragma unroll
        for (int nt = 0; nt < NT; nt++) {
            const int gc = wn0 + nt * 16 + lr;
#pragma unroll
            for (int r = 0; r < 4; r++) {
                const int gr = row0 + mt * 16 + quad * 4 + r;
                float v = acc[mt][nt][r];
                if (MODE == 0) {
                    if (gr < M && gc < Nout) outf[(long)gr * Nout + gc] = v + bias[gc];
                } else if (MODE == 1) {
                    if (gr < M) oh[(long)gr * 128 + gc] = f2bf(v * row_scale[gr]);
                } else {
                    float x = v + bias[gc];     // pad rows: A-planes are zeroed -> x=bias, harmless
                    unsigned short hh = f2bf(x);
                    unsigned short ll = f2bf(x - bf2f(hh));
                    long idx = ((((long)by * 4 + (gc >> 5)) * 4 + ((gc >> 3) & 3)) * 64
                                + (mt * 16 + quad * 4 + r)) * 8 + (gc & 7);
                    oh[idx] = hh;
                    ol[idx] = ll;
                }
            }
        }
    }
}

// ------------------------------------------------ D1: hist (256) + wprep (72) + A-split (782)
// 1024 threads. Partials chunk-major u16. A-split: pure streaming, no LDS, no
// barriers, all 1024 threads: tid -> (k4=tid&3, row=(tid>>2)&63, t=tid>>8).
// Reads 128B-granular (4 lanes x 32B contiguous), writes 256B-granular.
__global__ __launch_bounds__(1024) void hist_prep(
        const int* __restrict__ src, const int* __restrict__ dst,
        unsigned short* __restrict__ p_out, unsigned short* __restrict__ p_in, int E,
        const float* __restrict__ Wp, const float* __restrict__ W1,
        const float* __restrict__ W2, const float* __restrict__ Wc,
        unsigned short* __restrict__ ph, unsigned short* __restrict__ pl,
        unsigned short* __restrict__ h1h, unsigned short* __restrict__ h1l,
        unsigned short* __restrict__ h2h, unsigned short* __restrict__ h2l,
        unsigned short* __restrict__ chh, unsigned short* __restrict__ cll,
        const float* __restrict__ nf,
        unsigned short* __restrict__ nfh, unsigned short* __restrict__ nfl) {
    __shared__ int ho[RSZ];
    __shared__ int hd[RSZ];
    const int t = threadIdx.x;
    if (blockIdx.x < NRG * CHP) {
        const int r = blockIdx.x & 7;        // linear id = r + 8*b (XCD pinning)
        const int b = blockIdx.x >> 3;
        for (int i = t; i < RSZ; i += 1024) { ho[i] = 0; hd[i] = 0; }
        __syncthreads();
        const int base = r * RSZ;
        const int CE = (E + CHP - 1) / CHP;
        const int e0 = b * CE, e1 = min(E, e0 + CE);
#pragma unroll 4
        for (int e = e0 + t; e < e1; e += 1024) {
            int s = src[e], d = dst[e];
            unsigned so = (unsigned)(s - base);
            unsigned dof = (unsigned)(d - base);
            if (so < (unsigned)RSZ) atomicAdd(&ho[so], 1);
            if (dof < (unsigned)RSZ) atomicAdd(&hd[dof], 1);
        }
        __syncthreads();
        const long po = ((long)r * CHP + b) * RSZ;   // even
        unsigned* o32 = (unsigned*)&p_out[po];
        unsigned* i32 = (unsigned*)&p_in[po];
        for (int i = t; i < RSZ / 2; i += 1024) {
            o32[i] = (unsigned)ho[2 * i] | ((unsigned)ho[2 * i + 1] << 16);
            i32[i] = (unsigned)hd[2 * i] | ((unsigned)hd[2 * i + 1] << 16);
        }
        return;
    }
    if (blockIdx.x < NRG * CHP + 72) {
        // weight transpose + hi/lo split -> DMA layout (73728 = 72*1024 elems)
        int i = (blockIdx.x - NRG * CHP) * 1024 + t;
        const float* W; unsigned short *Bh, *Bl; int K, N, Np, j;
        if (i < 32768)        { W = Wp; Bh = ph;  Bl = pl;  K = 256; N = 128; Np = 128; j = i; }
        else if (i < 49152)   { W = W1; Bh = h1h; Bl = h1l; K = 128; N = 128; Np = 128; j = i - 32768; }
        else if (i < 65536)   { W = W2; Bh = h2h; Bl = h2l; K = 128; N = 128; Np = 128; j = i - 49152; }
        else if (i < 73728)   { W = Wc; Bh = chh; Bl = cll; K = 128; N = 40;  Np = 64;  j = i - 65536; }
        else return;
        int n = j / K, k = j % K;
        float v = (n < N) ? W[(long)k * N + n] : 0.f;
        unsigned short hh = f2bf(v);
        unsigned short ll = f2bf(v - bf2f(hh));
        long di = (((long)(k >> 5) * 4 + ((k >> 3) & 3)) * Np + n) * 8 + (k & 7);
        Bh[di] = hh;
        Bl[di] = ll;
        return;
    }
    // ---- A-split: rb-th 64-row block of n_feats -> nfh/nfl planes (NK=8)
    // streaming: no LDS, no barriers, all 1024 threads active.
    const int rb   = blockIdx.x - (NRG * CHP + 72);
    const int k4   = t & 3;
    const int row  = (t >> 2) & 63;
    const int tq   = t >> 8;                 // 0..3
    const int grow = rb * 64 + row;
    const float* rp = &nf[(long)grow * F];
#pragma unroll
    for (int hh2 = 0; hh2 < 2; hh2++) {
        const int tt = tq * 2 + hh2;         // k-step 0..7
        float4 v0 = make_float4(0.f, 0.f, 0.f, 0.f);
        float4 v1 = make_float4(0.f, 0.f, 0.f, 0.f);
        if (grow < NN) {
            v0 = *(const float4*)&rp[tt * 32 + k4 * 8];
            v1 = *(const float4*)&rp[tt * 32 + k4 * 8 + 4];
        }
        unsigned short a0 = f2bf(v0.x), a1 = f2bf(v0.y), a2 = f2bf(v0.z), a3 = f2bf(v0.w);
        unsigned short a4 = f2bf(v1.x), a5 = f2bf(v1.y), a6 = f2bf(v1.z), a7 = f2bf(v1.w);
        unsigned short b0 = f2bf(v0.x - bf2f(a0)), b1 = f2bf(v0.y - bf2f(a1));
        unsigned short b2 = f2bf(v0.z - bf2f(a2)), b3 = f2bf(v0.w - bf2f(a3));
        unsigned short b4 = f2bf(v1.x - bf2f(a4)), b5 = f2bf(v1.y - bf2f(a5));
        unsigned short b6 = f2bf(v1.z - bf2f(a6)), b7 = f2bf(v1.w - bf2f(a7));
        uint4 hv, lv;
        hv.x = (unsigned)a0 | ((unsigned)a1 << 16);
        hv.y = (unsigned)a2 | ((unsigned)a3 << 16);
        hv.z = (unsigned)a4 | ((unsigned)a5 << 16);
        hv.w = (unsigned)a6 | ((unsigned)a7 << 16);
        lv.x = (unsigned)b0 | ((unsigned)b1 << 16);
        lv.y = (unsigned)b2 | ((unsigned)b3 << 16);
        lv.z = (unsigned)b4 | ((unsigned)b5 << 16);
        lv.w = (unsigned)b6 | ((unsigned)b7 << 16);
        const long base = ((((long)rb * 8 + tt) * 4 + k4) * 64 + row) * 8;
        *(uint4*)&nfh[base] = hv;
        *(uint4*)&nfl[base] = lv;
    }
}

// ------------------------------------------------ D2: merge_scan (196) + proj GEMM (782)
__global__ __launch_bounds__(256) void merge_proj(
        const unsigned short* __restrict__ p_out, unsigned short* __restrict__ p_in,
        int* __restrict__ cnt_in, float* __restrict__ rs_out, float* __restrict__ rs_in,
        int* __restrict__ row_start, int* __restrict__ block_sums, int n, int nb,
        const unsigned short* __restrict__ Ah, const unsigned short* __restrict__ Al,
        const unsigned short* __restrict__ Bh, const unsigned short* __restrict__ Bl,
        const float* __restrict__ bias,
        unsigned short* __restrict__ xh, unsigned short* __restrict__ xl, int M) {
    if ((int)blockIdx.x < nb) {
        __shared__ int sh[256];
        const int t = threadIdx.x;
        const int i = blockIdx.x * 256 + t;
        int si = 0;
        if (i < n) {
            const int r = i / RSZ, off = i % RSZ;
            const long pb = (long)r * CHP * RSZ + off;
            int so = 0;
#pragma unroll 8
            for (int b = 0; b < CHP; b++) {
                so += p_out[pb + (long)b * RSZ];
                int v = p_in[pb + (long)b * RSZ];
                p_in[pb + (long)b * RSZ] = (unsigned short)si;
                si += v;
            }
            cnt_in[i] = si;
            rs_out[i] = rsqrtf((float)max(so, 1));
            rs_in[i]  = rsqrtf((float)max(si, 1));
        }
        sh[t] = si;
        __syncthreads();
#pragma unroll
        for (int off = 1; off < 256; off <<= 1) {
            int u = (t >= off) ? sh[t - off] : 0;
            __syncthreads();
            sh[t] += u;
            __syncthreads();
        }
        if (i < n) row_start[i] = sh[t] - si;
        if (t == 255) block_sums[blockIdx.x] = sh[255];
        return;
    }
    gemm_body<2, 128, 8>(blockIdx.x - nb, Ah, Al, Bh, Bl, bias, nullptr,
                         nullptr, xh, xl, M, 128);
}

// ------------------------------------------------ D3: scan_sums (1) + layer1 GEMM (782)
__global__ __launch_bounds__(256) void scansums_gemm(
        int* __restrict__ block_sums, int nb,
        const unsigned short* __restrict__ Ah, const unsigned short* __restrict__ Al,
        const unsigned short* __restrict__ Bh, const unsigned short* __restrict__ Bl,
        const float* __restrict__ row_scale, unsigned short* __restrict__ outh, int M) {
    if (blockIdx.x == 0) {
        __shared__ int sh[256];
        const int t = threadIdx.x;
        const int v = (t < nb) ? block_sums[t] : 0;
        sh[t] = v;
        __syncthreads();
#pragma unroll
        for (int off = 1; off < 256; off <<= 1) {
            int u = (t >= off) ? sh[t - off] : 0;
            __syncthreads();
            sh[t] += u;
            __syncthreads();
        }
        if (t < nb) block_sums[t] = sh[t] - v;
        return;
    }
    gemm_body<1, 128, 4>(blockIdx.x - 1, Ah, Al, Bh, Bl, nullptr, row_scale,
                         nullptr, outh, nullptr, M, 128);
}

// ------------------------------------------------ standalone GEMM wrapper
template<int MODE, int BN, int NK>
__global__ __launch_bounds__(256) void gemm_std(
        const unsigned short* __restrict__ Ah, const unsigned short* __restrict__ Al,
        const unsigned short* __restrict__ Bh, const unsigned short* __restrict__ Bl,
        const float* __restrict__ bias, const float* __restrict__ row_scale,
        float* __restrict__ outf, unsigned short* __restrict__ oh,
        unsigned short* __restrict__ ol, int M, int Nout) {
    gemm_body<MODE, BN, NK>(blockIdx.x, Ah, Al, Bh, Bl, bias, row_scale,
                            outf, oh, ol, M, Nout);
}

// ------------------------------------------------ D4: CSR fill, 1024 threads
__global__ __launch_bounds__(1024) void fill_csr_part(
        const int* __restrict__ src, const int* __restrict__ dst,
        const int* __restrict__ row_start, const int* __restrict__ block_sums,
        const unsigned short* __restrict__ p_in,
        int* __restrict__ csr_src, int E, int n_nodes) {
    __shared__ int cur[RSZ];
    const int r = blockIdx.x;
    const int b = blockIdx.y;
    const int base = r * RSZ;
    const long po = ((long)r * CHP + b) * RSZ;
    for (int i = threadIdx.x; i < RSZ; i += 1024) {
        int node = base + i;
        int rs = (node < n_nodes) ? (row_start[node] + block_sums[node >> 8]) : 0;
        cur[i] = rs + (int)p_in[po + i];
    }
    __syncthreads();
    const int CE = (E + CHP - 1) / CHP;
    const int e0 = b * CE, e1 = min(E, e0 + CE);
#pragma unroll 8
    for (int e = e0 + threadIdx.x; e < e1; e += 1024) {
        int d = dst[e];
        unsigned dof = (unsigned)(d - base);
        if (dof < (unsigned)RSZ) {
            int pos = atomicAdd(&cur[dof], 1);   // LDS atomic
            csr_src[pos] = src[e];
        }
    }
}

// ---------------------------------------------------------------- aggregation (bf16 h)
// out: hi/lo split planes in the GEMM A layout (NK'=4) -> next GEMM DMA-stages it.
__global__ __launch_bounds__(256) void aggregate_bf16(
        const uint4* __restrict__ h4, const int* __restrict__ csr_src,
        const int* __restrict__ row_start, const int* __restrict__ block_sums,
        const int* __restrict__ cnt_in,
        const float* __restrict__ rs_in, const float* __restrict__ bias,
        unsigned short* __restrict__ oh, unsigned short* __restrict__ ol, int nodes) {
    const int wave = threadIdx.x >> 6;
    const int lane = threadIdx.x & 63;
    const int grp  = lane >> 4;        // 0..3 = neighbor slot
    const int sl   = lane & 15;        // uint4 index in row
    const int v = blockIdx.x * 4 + wave;
    if (v >= nodes) return;
    const int s0  = row_start[v] + block_sums[v >> 8];
    const int cnt = cnt_in[v];

    float ax0 = 0.f, ay0 = 0.f, ax1 = 0.f, ay1 = 0.f;
    float ax2 = 0.f, ay2 = 0.f, ax3 = 0.f, ay3 = 0.f;
    int i0 = 0;
    for (; i0 + 8 <= cnt; i0 += 8) {               // 8 neighbors in flight
        int sA = csr_src[s0 + i0 + grp];
        int sB = csr_src[s0 + i0 + 4 + grp];
        uint4 uA = h4[(long)sA * 16 + sl];
        uint4 uB = h4[(long)sB * 16 + sl];
        ax0 += __uint_as_float(uA.x << 16) + __uint_as_float(uB.x << 16);
        ay0 += __uint_as_float(uA.x & 0xffff0000u) + __uint_as_float(uB.x & 0xffff0000u);
        ax1 += __uint_as_float(uA.y << 16) + __uint_as_float(uB.y << 16);
        ay1 += __uint_as_float(uA.y & 0xffff0000u) + __uint_as_float(uB.y & 0xffff0000u);
        ax2 += __uint_as_float(uA.z << 16) + __uint_as_float(uB.z << 16);
        ay2 += __uint_as_float(uA.z & 0xffff0000u) + __uint_as_float(uB.z & 0xffff0000u);
        ax3 += __uint_as_float(uA.w << 16) + __uint_as_float(uB.w << 16);
        ay3 += __uint_as_float(uA.w & 0xffff0000u) + __uint_as_float(uB.w & 0xffff0000u);
    }
    for (; i0 + 4 <= cnt; i0 += 4) {
        int s = csr_src[s0 + i0 + grp];
        uint4 u = h4[(long)s * 16 + sl];
        ax0 += __uint_as_float(u.x << 16); ay0 += __uint_as_float(u.x & 0xffff0000u);
        ax1 += __uint_as_float(u.y << 16); ay1 += __uint_as_float(u.y & 0xffff0000u);
        ax2 += __uint_as_float(u.z << 16); ay2 += __uint_as_float(u.z & 0xffff0000u);
        ax3 += __uint_as_float(u.w << 16); ay3 += __uint_as_float(u.w & 0xffff0000u);
    }
    if (i0 + grp < cnt) {                          // 0..3 tail neighbors
        int s = csr_src[s0 + i0 + grp];
        uint4 u = h4[(long)s * 16 + sl];
        ax0 += __uint_as_float(u.x << 16); ay0 += __uint_as_float(u.x & 0xffff0000u);
        ax1 += __uint_as_float(u.y << 16); ay1 += __uint_as_float(u.y & 0xffff0000u);
        ax2 += __uint_as_float(u.z << 16); ay2 += __uint_as_float(u.z & 0xffff0000u);
        ax3 += __uint_as_float(u.w << 16); ay3 += __uint_as_float(u.w & 0xffff0000u);
    }
    // sum across the 4 lane-groups (bits 4,5 of lane)
    ax0 += __shfl_xor(ax0, 16); ay0 += __shfl_xor(ay0, 16);
    ax1 += __shfl_xor(ax1, 16); ay1 += __shfl_xor(ay1, 16);
    ax2 += __shfl_xor(ax2, 16); ay2 += __shfl_xor(ay2, 16);
    ax3 += __shfl_xor(ax3, 16); ay3 += __shfl_xor(ay3, 16);
    ax0 += __shfl_xor(ax0, 32); ay0 += __shfl_xor(ay0, 32);
    ax1 += __shfl_xor(ax1, 32); ay1 += __shfl_xor(ay1, 32);
    ax2 += __shfl_xor(ax2, 32); ay2 += __shfl_xor(ay2, 32);
    ax3 += __shfl_xor(ax3, 32); ay3 += __shfl_xor(ay3, 32);

    if (grp == 0) {                                // lanes 0..15: cols sl*8..sl*8+7
        const float rs = rs_in[v];
        const float2 b0 = ((const float2*)bias)[sl * 4 + 0];
        const float2 b1 = ((const float2*)bias)[sl * 4 + 1];
        const float2 b2 = ((const float2*)bias)[sl * 4 + 2];
        const float2 b3 = ((const float2*)bias)[sl * 4 + 3];
        float w0 = fmaxf(ax0 * rs + b0.x, 0.f), w1 = fmaxf(ay0 * rs + b0.y, 0.f);
        float w2 = fmaxf(ax1 * rs + b1.x, 0.f), w3 = fmaxf(ay1 * rs + b1.y, 0.f);
        float w4 = fmaxf(ax2 * rs + b2.x, 0.f), w5 = fmaxf(ay2 * rs + b2.y, 0.f);
        float w6 = fmaxf(ax3 * rs + b3.x, 0.f), w7 = fmaxf(ay3 * rs + b3.y, 0.f);
        unsigned short h0 = f2bf(w0), h1 = f2bf(w1), h2 = f2bf(w2), h3 = f2bf(w3);
        unsigned short h4v = f2bf(w4), h5 = f2bf(w5), h6 = f2bf(w6), h7 = f2bf(w7);
        uint4 hv, lv;
        hv.x = (unsigned)h0 | ((unsigned)h1 << 16);
        hv.y = (unsigned)h2 | ((unsigned)h3 << 16);
        hv.z = (unsigned)h4v | ((unsigned)h5 << 16);
        hv.w = (unsigned)h6 | ((unsigned)h7 << 16);
        unsigned short l0 = f2bf(w0 - bf2f(h0)), l1 = f2bf(w1 - bf2f(h1));
        unsigned short l2 = f2bf(w2 - bf2f(h2)), l3 = f2bf(w3 - bf2f(h3));
        unsigned short l4 = f2bf(w4 - bf2f(h4v)), l5 = f2bf(w5 - bf2f(h5));
        unsigned short l6 = f2bf(w6 - bf2f(h6)), l7 = f2bf(w7 - bf2f(h7));
        lv.x = (unsigned)l0 | ((unsigned)l1 << 16);
        lv.y = (unsigned)l2 | ((unsigned)l3 << 16);
        lv.z = (unsigned)l4 | ((unsigned)l5 << 16);
        lv.w = (unsigned)l6 | ((unsigned)l7 << 16);
        long chunk = (((long)(v >> 6) * 4 + (sl >> 2)) * 4 + (sl & 3)) * 64 + (v & 63);
        *(uint4*)&oh[chunk * 8] = hv;
        *(uint4*)&ol[chunk * 8] = lv;
    }
}

// ---------------------------------------------------------------- launch
extern "C" void kernel_launch(void* const* d_in, const int* in_sizes, int n_in,
                              void* d_out, int out_size, void* d_ws, size_t ws_size,
                              hipStream_t stream) {
    const float* n_feats = (const float*)d_in[0];
    const int*   src     = (const int*)d_in[1];
    const int*   dst     = (const int*)d_in[2];
    const float* Wp      = (const float*)d_in[3];
    const float* bp      = (const float*)d_in[4];
    const float* W1      = (const float*)d_in[5];
    const float* b1      = (const float*)d_in[6];
    const float* W2      = (const float*)d_in[7];
    const float* b2      = (const float*)d_in[8];
    const float* Wc      = (const float*)d_in[9];
    const float* bc      = (const float*)d_in[10];
    float* out = (float*)d_out;
    const int E = in_sizes[1];

    const long PSZ = (long)NRG * CHP * RSZ;    // partials: 1,638,400 u16 (3.28 MB)
    const long XPL = (long)GBK * 4 * 2048;     // x-plane elems (K=128 layout)
    const long NPL = (long)GBK * 8 * 2048;     // n_feats-plane elems (K=256 layout)

    // workspace layout (~101 MB of 256 MiB)
    char* ws = (char*)d_ws;
    unsigned short* hbuf  = (unsigned short*)ws;                    // NN*H bf16
    unsigned short* xh    = hbuf + (long)NN * H;                    // XPL
    unsigned short* xl    = xh + XPL;
    unsigned short* nfh   = xl + XPL;                               // NPL
    unsigned short* nfl   = nfh + NPL;
    unsigned short* bt_ph = nfl + NPL;                              // 8*4*128*8
    unsigned short* bt_pl = bt_ph + 32768;
    unsigned short* bt_1h = bt_pl + 32768;                          // 4*4*128*8
    unsigned short* bt_1l = bt_1h + 16384;
    unsigned short* bt_2h = bt_1l + 16384;
    unsigned short* bt_2l = bt_2h + 16384;
    unsigned short* bt_ch = bt_2l + 16384;                          // 4*4*64*8
    unsigned short* bt_cl = bt_ch + 8192;
    int*   cnt_in     = (int*)(bt_cl + 8192);                       // N
    int*   row_start  = cnt_in + NN;                                // N (within-block excl)
    float* rs_out     = (float*)(row_start + NN);                   // N
    float* rs_in      = rs_out + NN;                                // N
    int*   block_sums = (int*)(rs_in + NN);                         // 256
    unsigned short* p_out = (unsigned short*)(block_sums + 256);    // PSZ u16
    unsigned short* p_in  = p_out + PSZ;                            // PSZ u16
    int*   csr_src    = (int*)(p_in + PSZ);                         // E

    const int NB = (NN + 255) / 256;    // 196

    // D1: histograms (256, XCD-pinned) + weight prep (72) + n_feats split (782)
    hist_prep<<<NRG * CHP + 72 + GBK, 1024, 0, stream>>>(
        src, dst, p_out, p_in, E, Wp, W1, W2, Wc,
        bt_ph, bt_pl, bt_1h, bt_1l, bt_2h, bt_2l, bt_ch, bt_cl,
        n_feats, nfh, nfl);
    // D2: merge+scan (196) + proj GEMM (782): xh/xl = split(n_feats @ Wp + bp)
    merge_proj<<<NB + GBK, 256, 0, stream>>>(
        p_out, p_in, cnt_in, rs_out, rs_in, row_start, block_sums, NN, NB,
        nfh, nfl, bt_ph, bt_pl, bp, xh, xl, NN);
    // D3: scan of block sums (1) + layer-1 GEMM (782): hbuf = bf16((x@W1)*rs_out)
    scansums_gemm<<<1 + GBK, 256, 0, stream>>>(
        block_sums, NB, xh, xl, bt_1h, bt_1l, rs_out, hbuf, NN);
    // D4: CSR fill (no global atomics), 1024 threads
    fill_csr_part<<<dim3(NRG, CHP), 1024, 0, stream>>>(
        src, dst, row_start, block_sums, p_in, csr_src, E, NN);
    // D5: aggregate 1 -> xh/xl = split(relu(rs_in * (A hbuf) + b1))
    aggregate_bf16<<<(NN + 3) / 4, 256, 0, stream>>>(
        (const uint4*)hbuf, csr_src, row_start, block_sums, cnt_in, rs_in, b1, xh, xl, NN);
    // D6: layer-2 GEMM: hbuf = bf16((x@W2)*rs_out)
    gemm_std<1, 128, 4><<<GBK, 256, 0, stream>>>(
        xh, xl, bt_2h, bt_2l, nullptr, rs_out, nullptr, hbuf, nullptr, NN, 128);
    // D7: aggregate 2 -> xh/xl
    aggregate_bf16<<<(NN + 3) / 4, 256, 0, stream>>>(
        (const uint4*)hbuf, csr_src, row_start, block_sums, cnt_in, rs_in, b2, xh, xl, NN);
    // D8: classifier: out = x @ Wc + bc (store-masked to 40 cols)
    gemm_std<0, 64, 4><<<GBK, 256, 0, stream>>>(
        xh, xl, bt_ch, bt_cl, bc, nullptr, out, nullptr, nullptr, NN, C);
}

// Round 4
// 291.134 us; speedup vs baseline: 1.0322x; 1.0031x over previous
//
#include <hip/hip_runtime.h>

// Problem constants (from reference setup_inputs)
constexpr int NN = 50000;   // nodes
constexpr int H  = 128;     // hidden
constexpr int F  = 256;     // input features
constexpr int C  = 40;      // classes

// graph-prepass partitioning: 8 ranges of 6400 nodes, 32 chunks, 1024-thread
// hist/fill blocks. hist linear ids 0..255: id%8 = range => XCD pinning.
constexpr int RSZ = 6400;
constexpr int NRG = 8;
constexpr int CHP = 32;     // partial chunks (merge chain length)
constexpr int GBK = (NN + 63) / 64;   // 782 GEMM row-blocks

typedef short bf16x8 __attribute__((ext_vector_type(8)));
typedef float f32x4  __attribute__((ext_vector_type(4)));

__device__ inline unsigned short f2bf(float f) {          // RNE fp32 -> bf16
    unsigned u = __float_as_uint(f);
    u += 0x7fff + ((u >> 16) & 1);
    return (unsigned short)(u >> 16);
}
__device__ inline float bf2f(unsigned short s) {
    return __uint_as_float(((unsigned)s) << 16);
}

// ------------------------------------------------ GEMM body (shared device fn)
// Skinny GEMM (N<=128, K<=256): B is L2-resident -> NO LDS, NO barriers.
// A-fragments and B-fragments load global->VGPR directly (coalesced via the
// pre-split chunk layout); fully-unrolled K-loop lets the compiler hoist loads.
//   A plane chunk(rb,t,k4,row) = ((rb*NK+t)*4+k4)*64+row, 8 bf16 each
//   B plane chunk(t,k4,col)    = (t*4+k4)*BN+col
// MODE 0: outf[gr*Nout+gc] = acc + bias (gc<Nout), fp32 (classifier)
// MODE 1: oh = row-major bf16(acc*row_scale)  (feeds aggregate)
// MODE 2: oh/ol = hi/lo split of (acc + bias) in A-plane layout keyed NK'=4
template<int MODE, int BN, int NK>
__device__ __forceinline__ void gemm_body(
        int by,
        const unsigned short* __restrict__ Ah, const unsigned short* __restrict__ Al,
        const unsigned short* __restrict__ Bh, const unsigned short* __restrict__ Bl,
        const float* __restrict__ bias, const float* __restrict__ row_scale,
        float* __restrict__ outf, unsigned short* __restrict__ oh,
        unsigned short* __restrict__ ol, int M, int Nout) {
    constexpr int NT = BN / 64;

    const int tid  = threadIdx.x;
    const int wave = tid >> 6;
    const int lane = tid & 63;
    const int quad = lane >> 4;
    const int lr   = lane & 15;
    const int row0 = by * 64;
    const int wn0  = wave * (BN / 4);

    f32x4 acc[4][NT];
#pragma unroll
    for (int mt = 0; mt < 4; mt++)
#pragma unroll
        for (int nt = 0; nt < NT; nt++)
            acc[mt][nt] = (f32x4){0.f, 0.f, 0.f, 0.f};

    // per-lane element offsets (in ushort units)
    const unsigned short* aH = Ah + ((long)by * NK) * 2048 + (quad * 64 + lr) * 8;
    const unsigned short* aL = Al + ((long)by * NK) * 2048 + (quad * 64 + lr) * 8;
    const unsigned short* bH = Bh + (quad * BN + wn0 + lr) * 8;
    const unsigned short* bL = Bl + (quad * BN + wn0 + lr) * 8;

#pragma unroll
    for (int t = 0; t < NK; t++) {
        bf16x8 ah[4], av[4], bh[NT], bv[NT];
#pragma unroll
        for (int mt = 0; mt < 4; mt++) {
            ah[mt] = *(const bf16x8*)&aH[t * 2048 + mt * 128];   // mt*16 rows * 8
            av[mt] = *(const bf16x8*)&aL[t * 2048 + mt * 128];
        }
#pragma unroll
        for (int nt = 0; nt < NT; nt++) {
            bh[nt] = *(const bf16x8*)&bH[t * 4 * BN * 8 + nt * 128];
            bv[nt] = *(const bf16x8*)&bL[t * 4 * BN * 8 + nt * 128];
        }
#pragma unroll
        for (int mt = 0; mt < 4; mt++)
#pragma unroll
            for (int nt = 0; nt < NT; nt++) {
                acc[mt][nt] = __builtin_amdgcn_mfma_f32_16x16x32_bf16(ah[mt], bh[nt], acc[mt][nt], 0, 0, 0);
                acc[mt][nt] = __builtin_amdgcn_mfma_f32_16x16x32_bf16(av[mt], bh[nt], acc[mt][nt], 0, 0, 0);
                acc[mt][nt] = __builtin_amdgcn_mfma_f32_16x16x32_bf16(ah[mt], bv[nt], acc[mt][nt], 0, 0, 0);
            }
    }

#pragma unroll
    for (int mt = 0; mt < 4; mt++) {
#pragma unroll
        for (int nt = 0; nt < NT; nt++) {
            const int gc = wn0 + nt * 16 + lr;
#pragma unroll
            for (int r = 0; r < 4; r++) {
                const int gr = row0 + mt * 16 + quad * 4 + r;
                float v = acc[mt][nt][r];
                if (MODE == 0) {
                    if (gr < M && gc < Nout) outf[(long)gr * Nout + gc] = v + bias[gc];
                } else if (MODE == 1) {
                    if (gr < M) oh[(long)gr * 128 + gc] = f2bf(v * row_scale[gr]);
                } else {
                    float x = v + bias[gc];     // pad rows: A-planes are zeroed -> x=bias, harmless
                    unsigned short hh = f2bf(x);
                    unsigned short ll = f2bf(x - bf2f(hh));
                    long idx = ((((long)by * 4 + (gc >> 5)) * 4 + ((gc >> 3) & 3)) * 64
                                + (mt * 16 + quad * 4 + r)) * 8 + (gc & 7);
                    oh[idx] = hh;
                    ol[idx] = ll;
                }
            }
        }
    }
}

// ------------------------------------------------ D1: hist (256) + wprep (72) + A-split (782)
// 1024 threads. Partials chunk-major u16. A-split: pure streaming, no LDS, no
// barriers, all 1024 threads: tid -> (k4=tid&3, row=(tid>>2)&63, t=tid>>8).
// Reads 128B-granular (4 lanes x 32B contiguous), writes 256B-granular.
__global__ __launch_bounds__(1024) void hist_prep(
        const int* __restrict__ src, const int* __restrict__ dst,
        unsigned short* __restrict__ p_out, unsigned short* __restrict__ p_in, int E,
        const float* __restrict__ Wp, const float* __restrict__ W1,
        const float* __restrict__ W2, const float* __restrict__ Wc,
        unsigned short* __restrict__ ph, unsigned short* __restrict__ pl,
        unsigned short* __restrict__ h1h, unsigned short* __restrict__ h1l,
        unsigned short* __restrict__ h2h, unsigned short* __restrict__ h2l,
        unsigned short* __restrict__ chh, unsigned short* __restrict__ cll,
        const float* __restrict__ nf,
        unsigned short* __restrict__ nfh, unsigned short* __restrict__ nfl) {
    __shared__ int ho[RSZ];
    __shared__ int hd[RSZ];
    const int t = threadIdx.x;
    if (blockIdx.x < NRG * CHP) {
        const int r = blockIdx.x & 7;        // linear id = r + 8*b (XCD pinning)
        const int b = blockIdx.x >> 3;
        for (int i = t; i < RSZ; i += 1024) { ho[i] = 0; hd[i] = 0; }
        __syncthreads();
        const int base = r * RSZ;
        const int CE = (E + CHP - 1) / CHP;
        const int e0 = b * CE, e1 = min(E, e0 + CE);
#pragma unroll 4
        for (int e = e0 + t; e < e1; e += 1024) {
            int s = src[e], d = dst[e];
            unsigned so = (unsigned)(s - base);
            unsigned dof = (unsigned)(d - base);
            if (so < (unsigned)RSZ) atomicAdd(&ho[so], 1);
            if (dof < (unsigned)RSZ) atomicAdd(&hd[dof], 1);
        }
        __syncthreads();
        const long po = ((long)r * CHP + b) * RSZ;   // even
        unsigned* o32 = (unsigned*)&p_out[po];
        unsigned* i32 = (unsigned*)&p_in[po];
        for (int i = t; i < RSZ / 2; i += 1024) {
            o32[i] = (unsigned)ho[2 * i] | ((unsigned)ho[2 * i + 1] << 16);
            i32[i] = (unsigned)hd[2 * i] | ((unsigned)hd[2 * i + 1] << 16);
        }
        return;
    }
    if (blockIdx.x < NRG * CHP + 72) {
        // weight transpose + hi/lo split -> DMA layout (73728 = 72*1024 elems)
        int i = (blockIdx.x - NRG * CHP) * 1024 + t;
        const float* W; unsigned short *Bh, *Bl; int K, N, Np, j;
        if (i < 32768)        { W = Wp; Bh = ph;  Bl = pl;  K = 256; N = 128; Np = 128; j = i; }
        else if (i < 49152)   { W = W1; Bh = h1h; Bl = h1l; K = 128; N = 128; Np = 128; j = i - 32768; }
        else if (i < 65536)   { W = W2; Bh = h2h; Bl = h2l; K = 128; N = 128; Np = 128; j = i - 49152; }
        else if (i < 73728)   { W = Wc; Bh = chh; Bl = cll; K = 128; N = 40;  Np = 64;  j = i - 65536; }
        else return;
        int n = j / K, k = j % K;
        float v = (n < N) ? W[(long)k * N + n] : 0.f;
        unsigned short hh = f2bf(v);
        unsigned short ll = f2bf(v - bf2f(hh));
        long di = (((long)(k >> 5) * 4 + ((k >> 3) & 3)) * Np + n) * 8 + (k & 7);
        Bh[di] = hh;
        Bl[di] = ll;
        return;
    }
    // ---- A-split: rb-th 64-row block of n_feats -> nfh/nfl planes (NK=8)
    // streaming: no LDS, no barriers, all 1024 threads active.
    const int rb   = blockIdx.x - (NRG * CHP + 72);
    const int k4   = t & 3;
    const int row  = (t >> 2) & 63;
    const int tq   = t >> 8;                 // 0..3
    const int grow = rb * 64 + row;
    const float* rp = &nf[(long)grow * F];
#pragma unroll
    for (int hh2 = 0; hh2 < 2; hh2++) {
        const int tt = tq * 2 + hh2;         // k-step 0..7
        float4 v0 = make_float4(0.f, 0.f, 0.f, 0.f);
        float4 v1 = make_float4(0.f, 0.f, 0.f, 0.f);
        if (grow < NN) {
            v0 = *(const float4*)&rp[tt * 32 + k4 * 8];
            v1 = *(const float4*)&rp[tt * 32 + k4 * 8 + 4];
        }
        unsigned short a0 = f2bf(v0.x), a1 = f2bf(v0.y), a2 = f2bf(v0.z), a3 = f2bf(v0.w);
        unsigned short a4 = f2bf(v1.x), a5 = f2bf(v1.y), a6 = f2bf(v1.z), a7 = f2bf(v1.w);
        unsigned short b0 = f2bf(v0.x - bf2f(a0)), b1 = f2bf(v0.y - bf2f(a1));
        unsigned short b2 = f2bf(v0.z - bf2f(a2)), b3 = f2bf(v0.w - bf2f(a3));
        unsigned short b4 = f2bf(v1.x - bf2f(a4)), b5 = f2bf(v1.y - bf2f(a5));
        unsigned short b6 = f2bf(v1.z - bf2f(a6)), b7 = f2bf(v1.w - bf2f(a7));
        uint4 hv, lv;
        hv.x = (unsigned)a0 | ((unsigned)a1 << 16);
        hv.y = (unsigned)a2 | ((unsigned)a3 << 16);
        hv.z = (unsigned)a4 | ((unsigned)a5 << 16);
        hv.w = (unsigned)a6 | ((unsigned)a7 << 16);
        lv.x = (unsigned)b0 | ((unsigned)b1 << 16);
        lv.y = (unsigned)b2 | ((unsigned)b3 << 16);
        lv.z = (unsigned)b4 | ((unsigned)b5 << 16);
        lv.w = (unsigned)b6 | ((unsigned)b7 << 16);
        const long base = ((((long)rb * 8 + tt) * 4 + k4) * 64 + row) * 8;
        *(uint4*)&nfh[base] = hv;
        *(uint4*)&nfl[base] = lv;
    }
}

// ------------------------------------------------ D2: merge_scan (196) + proj GEMM (782)
__global__ __launch_bounds__(256) void merge_proj(
        const unsigned short* __restrict__ p_out, unsigned short* __restrict__ p_in,
        int* __restrict__ cnt_in, float* __restrict__ rs_out, float* __restrict__ rs_in,
        int* __restrict__ row_start, int* __restrict__ block_sums, int n, int nb,
        const unsigned short* __restrict__ Ah, const unsigned short* __restrict__ Al,
        const unsigned short* __restrict__ Bh, const unsigned short* __restrict__ Bl,
        const float* __restrict__ bias,
        unsigned short* __restrict__ xh, unsigned short* __restrict__ xl, int M) {
    if ((int)blockIdx.x < nb) {
        __shared__ int sh[256];
        const int t = threadIdx.x;
        const int i = blockIdx.x * 256 + t;
        int si = 0;
        if (i < n) {
            const int r = i / RSZ, off = i % RSZ;
            const long pb = (long)r * CHP * RSZ + off;
            int so = 0;
#pragma unroll 8
            for (int b = 0; b < CHP; b++) {
                so += p_out[pb + (long)b * RSZ];
                int v = p_in[pb + (long)b * RSZ];
                p_in[pb + (long)b * RSZ] = (unsigned short)si;
                si += v;
            }
            cnt_in[i] = si;
            rs_out[i] = rsqrtf((float)max(so, 1));
            rs_in[i]  = rsqrtf((float)max(si, 1));
        }
        sh[t] = si;
        __syncthreads();
#pragma unroll
        for (int off = 1; off < 256; off <<= 1) {
            int u = (t >= off) ? sh[t - off] : 0;
            __syncthreads();
            sh[t] += u;
            __syncthreads();
        }
        if (i < n) row_start[i] = sh[t] - si;
        if (t == 255) block_sums[blockIdx.x] = sh[255];
        return;
    }
    gemm_body<2, 128, 8>(blockIdx.x - nb, Ah, Al, Bh, Bl, bias, nullptr,
                         nullptr, xh, xl, M, 128);
}

// ------------------------------------------------ D3: scan_sums (1) + layer1 GEMM (782)
__global__ __launch_bounds__(256) void scansums_gemm(
        int* __restrict__ block_sums, int nb,
        const unsigned short* __restrict__ Ah, const unsigned short* __restrict__ Al,
        const unsigned short* __restrict__ Bh, const unsigned short* __restrict__ Bl,
        const float* __restrict__ row_scale, unsigned short* __restrict__ outh, int M) {
    if (blockIdx.x == 0) {
        __shared__ int sh[256];
        const int t = threadIdx.x;
        const int v = (t < nb) ? block_sums[t] : 0;
        sh[t] = v;
        __syncthreads();
#pragma unroll
        for (int off = 1; off < 256; off <<= 1) {
            int u = (t >= off) ? sh[t - off] : 0;
            __syncthreads();
            sh[t] += u;
            __syncthreads();
        }
        if (t < nb) block_sums[t] = sh[t] - v;
        return;
    }
    gemm_body<1, 128, 4>(blockIdx.x - 1, Ah, Al, Bh, Bl, nullptr, row_scale,
                         nullptr, outh, nullptr, M, 128);
}

// ------------------------------------------------ standalone GEMM wrapper
template<int MODE, int BN, int NK>
__global__ __launch_bounds__(256) void gemm_std(
        const unsigned short* __restrict__ Ah, const unsigned short* __restrict__ Al,
        const unsigned short* __restrict__ Bh, const unsigned short* __restrict__ Bl,
        const float* __restrict__ bias, const float* __restrict__ row_scale,
        float* __restrict__ outf, unsigned short* __restrict__ oh,
        unsigned short* __restrict__ ol, int M, int Nout) {
    gemm_body<MODE, BN, NK>(blockIdx.x, Ah, Al, Bh, Bl, bias, row_scale,
                            outf, oh, ol, M, Nout);
}

// ------------------------------------------------ D4: CSR fill, 1024 threads
__global__ __launch_bounds__(1024) void fill_csr_part(
        const int* __restrict__ src, const int* __restrict__ dst,
        const int* __restrict__ row_start, const int* __restrict__ block_sums,
        const unsigned short* __restrict__ p_in,
        int* __restrict__ csr_src, int E, int n_nodes) {
    __shared__ int cur[RSZ];
    const int r = blockIdx.x;
    const int b = blockIdx.y;
    const int base = r * RSZ;
    const long po = ((long)r * CHP + b) * RSZ;
    for (int i = threadIdx.x; i < RSZ; i += 1024) {
        int node = base + i;
        int rs = (node < n_nodes) ? (row_start[node] + block_sums[node >> 8]) : 0;
        cur[i] = rs + (int)p_in[po + i];
    }
    __syncthreads();
    const int CE = (E + CHP - 1) / CHP;
    const int e0 = b * CE, e1 = min(E, e0 + CE);
#pragma unroll 8
    for (int e = e0 + threadIdx.x; e < e1; e += 1024) {
        int d = dst[e];
        unsigned dof = (unsigned)(d - base);
        if (dof < (unsigned)RSZ) {
            int pos = atomicAdd(&cur[dof], 1);   // LDS atomic
            csr_src[pos] = src[e];
        }
    }
}

// ---------------------------------------------------------------- aggregation (bf16 h)
// out: hi/lo split planes in the GEMM A layout (NK'=4) -> next GEMM reads direct.
__global__ __launch_bounds__(256) void aggregate_bf16(
        const uint4* __restrict__ h4, const int* __restrict__ csr_src,
        const int* __restrict__ row_start, const int* __restrict__ block_sums,
        const int* __restrict__ cnt_in,
        const float* __restrict__ rs_in, const float* __restrict__ bias,
        unsigned short* __restrict__ oh, unsigned short* __restrict__ ol, int nodes) {
    const int wave = threadIdx.x >> 6;
    const int lane = threadIdx.x & 63;
    const int grp  = lane >> 4;        // 0..3 = neighbor slot
    const int sl   = lane & 15;        // uint4 index in row
    const int v = blockIdx.x * 4 + wave;
    if (v >= nodes) return;
    const int s0  = row_start[v] + block_sums[v >> 8];
    const int cnt = cnt_in[v];

    float ax0 = 0.f, ay0 = 0.f, ax1 = 0.f, ay1 = 0.f;
    float ax2 = 0.f, ay2 = 0.f, ax3 = 0.f, ay3 = 0.f;
    int i0 = 0;
    for (; i0 + 8 <= cnt; i0 += 8) {               // 8 neighbors in flight
        int sA = csr_src[s0 + i0 + grp];
        int sB = csr_src[s0 + i0 + 4 + grp];
        uint4 uA = h4[(long)sA * 16 + sl];
        uint4 uB = h4[(long)sB * 16 + sl];
        ax0 += __uint_as_float(uA.x << 16) + __uint_as_float(uB.x << 16);
        ay0 += __uint_as_float(uA.x & 0xffff0000u) + __uint_as_float(uB.x & 0xffff0000u);
        ax1 += __uint_as_float(uA.y << 16) + __uint_as_float(uB.y << 16);
        ay1 += __uint_as_float(uA.y & 0xffff0000u) + __uint_as_float(uB.y & 0xffff0000u);
        ax2 += __uint_as_float(uA.z << 16) + __uint_as_float(uB.z << 16);
        ay2 += __uint_as_float(uA.z & 0xffff0000u) + __uint_as_float(uB.z & 0xffff0000u);
        ax3 += __uint_as_float(uA.w << 16) + __uint_as_float(uB.w << 16);
        ay3 += __uint_as_float(uA.w & 0xffff0000u) + __uint_as_float(uB.w & 0xffff0000u);
    }
    for (; i0 + 4 <= cnt; i0 += 4) {
        int s = csr_src[s0 + i0 + grp];
        uint4 u = h4[(long)s * 16 + sl];
        ax0 += __uint_as_float(u.x << 16); ay0 += __uint_as_float(u.x & 0xffff0000u);
        ax1 += __uint_as_float(u.y << 16); ay1 += __uint_as_float(u.y & 0xffff0000u);
        ax2 += __uint_as_float(u.z << 16); ay2 += __uint_as_float(u.z & 0xffff0000u);
        ax3 += __uint_as_float(u.w << 16); ay3 += __uint_as_float(u.w & 0xffff0000u);
    }
    if (i0 + grp < cnt) {                          // 0..3 tail neighbors
        int s = csr_src[s0 + i0 + grp];
        uint4 u = h4[(long)s * 16 + sl];
        ax0 += __uint_as_float(u.x << 16); ay0 += __uint_as_float(u.x & 0xffff0000u);
        ax1 += __uint_as_float(u.y << 16); ay1 += __uint_as_float(u.y & 0xffff0000u);
        ax2 += __uint_as_float(u.z << 16); ay2 += __uint_as_float(u.z & 0xffff0000u);
        ax3 += __uint_as_float(u.w << 16); ay3 += __uint_as_float(u.w & 0xffff0000u);
    }
    // sum across the 4 lane-groups (bits 4,5 of lane)
    ax0 += __shfl_xor(ax0, 16); ay0 += __shfl_xor(ay0, 16);
    ax1 += __shfl_xor(ax1, 16); ay1 += __shfl_xor(ay1, 16);
    ax2 += __shfl_xor(ax2, 16); ay2 += __shfl_xor(ay2, 16);
    ax3 += __shfl_xor(ax3, 16); ay3 += __shfl_xor(ay3, 16);
    ax0 += __shfl_xor(ax0, 32); ay0 += __shfl_xor(ay0, 32);
    ax1 += __shfl_xor(ax1, 32); ay1 += __shfl_xor(ay1, 32);
    ax2 += __shfl_xor(ax2, 32); ay2 += __shfl_xor(ay2, 32);
    ax3 += __shfl_xor(ax3, 32); ay3 += __shfl_xor(ay3, 32);

    if (grp == 0) {                                // lanes 0..15: cols sl*8..sl*8+7
        const float rs = rs_in[v];
        const float2 b0 = ((const float2*)bias)[sl * 4 + 0];
        const float2 b1 = ((const float2*)bias)[sl * 4 + 1];
        const float2 b2 = ((const float2*)bias)[sl * 4 + 2];
        const float2 b3 = ((const float2*)bias)[sl * 4 + 3];
        float w0 = fmaxf(ax0 * rs + b0.x, 0.f), w1 = fmaxf(ay0 * rs + b0.y, 0.f);
        float w2 = fmaxf(ax1 * rs + b1.x, 0.f), w3 = fmaxf(ay1 * rs + b1.y, 0.f);
        float w4 = fmaxf(ax2 * rs + b2.x, 0.f), w5 = fmaxf(ay2 * rs + b2.y, 0.f);
        float w6 = fmaxf(ax3 * rs + b3.x, 0.f), w7 = fmaxf(ay3 * rs + b3.y, 0.f);
        unsigned short h0 = f2bf(w0), h1 = f2bf(w1), h2 = f2bf(w2), h3 = f2bf(w3);
        unsigned short h4v = f2bf(w4), h5 = f2bf(w5), h6 = f2bf(w6), h7 = f2bf(w7);
        uint4 hv, lv;
        hv.x = (unsigned)h0 | ((unsigned)h1 << 16);
        hv.y = (unsigned)h2 | ((unsigned)h3 << 16);
        hv.z = (unsigned)h4v | ((unsigned)h5 << 16);
        hv.w = (unsigned)h6 | ((unsigned)h7 << 16);
        unsigned short l0 = f2bf(w0 - bf2f(h0)), l1 = f2bf(w1 - bf2f(h1));
        unsigned short l2 = f2bf(w2 - bf2f(h2)), l3 = f2bf(w3 - bf2f(h3));
        unsigned short l4 = f2bf(w4 - bf2f(h4v)), l5 = f2bf(w5 - bf2f(h5));
        unsigned short l6 = f2bf(w6 - bf2f(h6)), l7 = f2bf(w7 - bf2f(h7));
        lv.x = (unsigned)l0 | ((unsigned)l1 << 16);
        lv.y = (unsigned)l2 | ((unsigned)l3 << 16);
        lv.z = (unsigned)l4 | ((unsigned)l5 << 16);
        lv.w = (unsigned)l6 | ((unsigned)l7 << 16);
        long chunk = (((long)(v >> 6) * 4 + (sl >> 2)) * 4 + (sl & 3)) * 64 + (v & 63);
        *(uint4*)&oh[chunk * 8] = hv;
        *(uint4*)&ol[chunk * 8] = lv;
    }
}

// ---------------------------------------------------------------- launch
extern "C" void kernel_launch(void* const* d_in, const int* in_sizes, int n_in,
                              void* d_out, int out_size, void* d_ws, size_t ws_size,
                              hipStream_t stream) {
    const float* n_feats = (const float*)d_in[0];
    const int*   src     = (const int*)d_in[1];
    const int*   dst     = (const int*)d_in[2];
    const float* Wp      = (const float*)d_in[3];
    const float* bp      = (const float*)d_in[4];
    const float* W1      = (const float*)d_in[5];
    const float* b1      = (const float*)d_in[6];
    const float* W2      = (const float*)d_in[7];
    const float* b2      = (const float*)d_in[8];
    const float* Wc      = (const float*)d_in[9];
    const float* bc      = (const float*)d_in[10];
    float* out = (float*)d_out;
    const int E = in_sizes[1];

    const long PSZ = (long)NRG * CHP * RSZ;    // partials: 1,638,400 u16 (3.28 MB)
    const long XPL = (long)GBK * 4 * 2048;     // x-plane elems (K=128 layout)
    const long NPL = (long)GBK * 8 * 2048;     // n_feats-plane elems (K=256 layout)

    // workspace layout (~101 MB of 256 MiB)
    char* ws = (char*)d_ws;
    unsigned short* hbuf  = (unsigned short*)ws;                    // NN*H bf16
    unsigned short* xh    = hbuf + (long)NN * H;                    // XPL
    unsigned short* xl    = xh + XPL;
    unsigned short* nfh   = xl + XPL;                               // NPL
    unsigned short* nfl   = nfh + NPL;
    unsigned short* bt_ph = nfl + NPL;                              // 8*4*128*8
    unsigned short* bt_pl = bt_ph + 32768;
    unsigned short* bt_1h = bt_pl + 32768;                          // 4*4*128*8
    unsigned short* bt_1l = bt_1h + 16384;
    unsigned short* bt_2h = bt_1l + 16384;
    unsigned short* bt_2l = bt_2h + 16384;
    unsigned short* bt_ch = bt_2l + 16384;                          // 4*4*64*8
    unsigned short* bt_cl = bt_ch + 8192;
    int*   cnt_in     = (int*)(bt_cl + 8192);                       // N
    int*   row_start  = cnt_in + NN;                                // N (within-block excl)
    float* rs_out     = (float*)(row_start + NN);                   // N
    float* rs_in      = rs_out + NN;                                // N
    int*   block_sums = (int*)(rs_in + NN);                         // 256
    unsigned short* p_out = (unsigned short*)(block_sums + 256);    // PSZ u16
    unsigned short* p_in  = p_out + PSZ;                            // PSZ u16
    int*   csr_src    = (int*)(p_in + PSZ);                         // E

    const int NB = (NN + 255) / 256;    // 196

    // D1: histograms (256, XCD-pinned) + weight prep (72) + n_feats split (782)
    hist_prep<<<NRG * CHP + 72 + GBK, 1024, 0, stream>>>(
        src, dst, p_out, p_in, E, Wp, W1, W2, Wc,
        bt_ph, bt_pl, bt_1h, bt_1l, bt_2h, bt_2l, bt_ch, bt_cl,
        n_feats, nfh, nfl);
    // D2: merge+scan (196) + proj GEMM (782): xh/xl = split(n_feats @ Wp + bp)
    merge_proj<<<NB + GBK, 256, 0, stream>>>(
        p_out, p_in, cnt_in, rs_out, rs_in, row_start, block_sums, NN, NB,
        nfh, nfl, bt_ph, bt_pl, bp, xh, xl, NN);
    // D3: scan of block sums (1) + layer-1 GEMM (782): hbuf = bf16((x@W1)*rs_out)
    scansums_gemm<<<1 + GBK, 256, 0, stream>>>(
        block_sums, NB, xh, xl, bt_1h, bt_1l, rs_out, hbuf, NN);
    // D4: CSR fill (no global atomics), 1024 threads
    fill_csr_part<<<dim3(NRG, CHP), 1024, 0, stream>>>(
        src, dst, row_start, block_sums, p_in, csr_src, E, NN);
    // D5: aggregate 1 -> xh/xl = split(relu(rs_in * (A hbuf) + b1))
    aggregate_bf16<<<(NN + 3) / 4, 256, 0, stream>>>(
        (const uint4*)hbuf, csr_src, row_start, block_sums, cnt_in, rs_in, b1, xh, xl, NN);
    // D6: layer-2 GEMM: hbuf = bf16((x@W2)*rs_out)
    gemm_std<1, 128, 4><<<GBK, 256, 0, stream>>>(
        xh, xl, bt_2h, bt_2l, nullptr, rs_out, nullptr, hbuf, nullptr, NN, 128);
    // D7: aggregate 2 -> xh/xl
    aggregate_bf16<<<(NN + 3) / 4, 256, 0, stream>>>(
        (const uint4*)hbuf, csr_src, row_start, block_sums, cnt_in, rs_in, b2, xh, xl, NN);
    // D8: classifier: out = x @ Wc + bc (store-masked to 40 cols)
    gemm_std<0, 64, 4><<<GBK, 256, 0, stream>>>(
        xh, xl, bt_ch, bt_cl, bc, nullptr, out, nullptr, nullptr, NN, C);
}

// Round 5
// 263.438 us; speedup vs baseline: 1.1407x; 1.1051x over previous
//
#include <hip/hip_runtime.h>

// Problem constants (from reference setup_inputs)
constexpr int NN = 50000;   // nodes
constexpr int H  = 128;     // hidden
constexpr int F  = 256;     // input features
constexpr int C  = 40;      // classes

// graph-prepass partitioning: 8 ranges of 6400 nodes, 32 chunks, 1024-thread
// hist/fill blocks. hist linear ids 0..255: id%8 = range => XCD pinning.
constexpr int RSZ = 6400;
constexpr int NRG = 8;
constexpr int CHP = 32;     // partial chunks (merge chain length)
constexpr int GBK = (NN + 63) / 64;   // 782 GEMM row-blocks

typedef short bf16x8 __attribute__((ext_vector_type(8)));
typedef float f32x4  __attribute__((ext_vector_type(4)));

__device__ inline unsigned short f2bf(float f) {          // RNE fp32 -> bf16
    unsigned u = __float_as_uint(f);
    u += 0x7fff + ((u >> 16) & 1);
    return (unsigned short)(u >> 16);
}
__device__ inline float bf2f(unsigned short s) {
    return __uint_as_float(((unsigned)s) << 16);
}

// ------------------------------------------------ GEMM body (shared device fn)
// Skinny GEMM (N<=128, K<=256): B is L2-resident -> NO LDS, NO barriers.
// A-fragments and B-fragments load global->VGPR directly (coalesced via the
// pre-split chunk layout); fully-unrolled K-loop lets the compiler hoist loads.
//   A plane chunk(rb,t,k4,row) = ((rb*NK+t)*4+k4)*64+row, 8 bf16 each
//   B plane chunk(t,k4,col)    = (t*4+k4)*BN+col
// MODE 1: oh = row-major bf16(acc*row_scale)  (feeds aggregate)
// MODE 2: oh/ol = hi/lo split of (acc + bias) in A-plane layout keyed NK'=4
template<int MODE, int BN, int NK>
__device__ __forceinline__ void gemm_body(
        int by,
        const unsigned short* __restrict__ Ah, const unsigned short* __restrict__ Al,
        const unsigned short* __restrict__ Bh, const unsigned short* __restrict__ Bl,
        const float* __restrict__ bias, const float* __restrict__ row_scale,
        unsigned short* __restrict__ oh, unsigned short* __restrict__ ol,
        int M, int Nout) {
    constexpr int NT = BN / 64;

    const int tid  = threadIdx.x;
    const int wave = tid >> 6;
    const int lane = tid & 63;
    const int quad = lane >> 4;
    const int lr   = lane & 15;
    const int row0 = by * 64;
    const int wn0  = wave * (BN / 4);

    f32x4 acc[4][NT];
#pragma unroll
    for (int mt = 0; mt < 4; mt++)
#pragma unroll
        for (int nt = 0; nt < NT; nt++)
            acc[mt][nt] = (f32x4){0.f, 0.f, 0.f, 0.f};

    // per-lane element offsets (in ushort units)
    const unsigned short* aH = Ah + ((long)by * NK) * 2048 + (quad * 64 + lr) * 8;
    const unsigned short* aL = Al + ((long)by * NK) * 2048 + (quad * 64 + lr) * 8;
    const unsigned short* bH = Bh + (quad * BN + wn0 + lr) * 8;
    const unsigned short* bL = Bl + (quad * BN + wn0 + lr) * 8;

#pragma unroll
    for (int t = 0; t < NK; t++) {
        bf16x8 ah[4], av[4], bh[NT], bv[NT];
#pragma unroll
        for (int mt = 0; mt < 4; mt++) {
            ah[mt] = *(const bf16x8*)&aH[t * 2048 + mt * 128];   // mt*16 rows * 8
            av[mt] = *(const bf16x8*)&aL[t * 2048 + mt * 128];
        }
#pragma unroll
        for (int nt = 0; nt < NT; nt++) {
            bh[nt] = *(const bf16x8*)&bH[t * 4 * BN * 8 + nt * 128];
            bv[nt] = *(const bf16x8*)&bL[t * 4 * BN * 8 + nt * 128];
        }
#pragma unroll
        for (int mt = 0; mt < 4; mt++)
#pragma unroll
            for (int nt = 0; nt < NT; nt++) {
                acc[mt][nt] = __builtin_amdgcn_mfma_f32_16x16x32_bf16(ah[mt], bh[nt], acc[mt][nt], 0, 0, 0);
                acc[mt][nt] = __builtin_amdgcn_mfma_f32_16x16x32_bf16(av[mt], bh[nt], acc[mt][nt], 0, 0, 0);
                acc[mt][nt] = __builtin_amdgcn_mfma_f32_16x16x32_bf16(ah[mt], bv[nt], acc[mt][nt], 0, 0, 0);
            }
    }

#pragma unroll
    for (int mt = 0; mt < 4; mt++) {
#pragma unroll
        for (int nt = 0; nt < NT; nt++) {
            const int gc = wn0 + nt * 16 + lr;
#pragma unroll
            for (int r = 0; r < 4; r++) {
                const int gr = row0 + mt * 16 + quad * 4 + r;
                float v = acc[mt][nt][r];
                if (MODE == 1) {
                    if (gr < M) oh[(long)gr * 128 + gc] = f2bf(v * row_scale[gr]);
                } else {
                    float x = v + bias[gc];     // pad rows: A-planes are zeroed -> x=bias, harmless
                    unsigned short hh = f2bf(x);
                    unsigned short ll = f2bf(x - bf2f(hh));
                    long idx = ((((long)by * 4 + (gc >> 5)) * 4 + ((gc >> 3) & 3)) * 64
                                + (mt * 16 + quad * 4 + r)) * 8 + (gc & 7);
                    oh[idx] = hh;
                    ol[idx] = ll;
                }
            }
        }
    }
}

// ------------------------------------------------ D1: hist (256) + wprep (72) + A-split (782)
// 1024 threads. Partials chunk-major u16. A-split: pure streaming, no LDS, no
// barriers, all 1024 threads: tid -> (k4=tid&3, row=(tid>>2)&63, t=tid>>8).
__global__ __launch_bounds__(1024) void hist_prep(
        const int* __restrict__ src, const int* __restrict__ dst,
        unsigned short* __restrict__ p_out, unsigned short* __restrict__ p_in, int E,
        const float* __restrict__ Wp, const float* __restrict__ W1,
        const float* __restrict__ W2, const float* __restrict__ Wc,
        unsigned short* __restrict__ ph, unsigned short* __restrict__ pl,
        unsigned short* __restrict__ h1h, unsigned short* __restrict__ h1l,
        unsigned short* __restrict__ h2h, unsigned short* __restrict__ h2l,
        unsigned short* __restrict__ chh, unsigned short* __restrict__ cll,
        const float* __restrict__ nf,
        unsigned short* __restrict__ nfh, unsigned short* __restrict__ nfl) {
    __shared__ int ho[RSZ];
    __shared__ int hd[RSZ];
    const int t = threadIdx.x;
    if (blockIdx.x < NRG * CHP) {
        const int r = blockIdx.x & 7;        // linear id = r + 8*b (XCD pinning)
        const int b = blockIdx.x >> 3;
        for (int i = t; i < RSZ; i += 1024) { ho[i] = 0; hd[i] = 0; }
        __syncthreads();
        const int base = r * RSZ;
        const int CE = (E + CHP - 1) / CHP;
        const int e0 = b * CE, e1 = min(E, e0 + CE);
#pragma unroll 4
        for (int e = e0 + t; e < e1; e += 1024) {
            int s = src[e], d = dst[e];
            unsigned so = (unsigned)(s - base);
            unsigned dof = (unsigned)(d - base);
            if (so < (unsigned)RSZ) atomicAdd(&ho[so], 1);
            if (dof < (unsigned)RSZ) atomicAdd(&hd[dof], 1);
        }
        __syncthreads();
        const long po = ((long)r * CHP + b) * RSZ;   // even
        unsigned* o32 = (unsigned*)&p_out[po];
        unsigned* i32 = (unsigned*)&p_in[po];
        for (int i = t; i < RSZ / 2; i += 1024) {
            o32[i] = (unsigned)ho[2 * i] | ((unsigned)ho[2 * i + 1] << 16);
            i32[i] = (unsigned)hd[2 * i] | ((unsigned)hd[2 * i + 1] << 16);
        }
        return;
    }
    if (blockIdx.x < NRG * CHP + 72) {
        // weight transpose + hi/lo split -> DMA layout (73728 = 72*1024 elems)
        int i = (blockIdx.x - NRG * CHP) * 1024 + t;
        const float* W; unsigned short *Bh, *Bl; int K, N, Np, j;
        if (i < 32768)        { W = Wp; Bh = ph;  Bl = pl;  K = 256; N = 128; Np = 128; j = i; }
        else if (i < 49152)   { W = W1; Bh = h1h; Bl = h1l; K = 128; N = 128; Np = 128; j = i - 32768; }
        else if (i < 65536)   { W = W2; Bh = h2h; Bl = h2l; K = 128; N = 128; Np = 128; j = i - 49152; }
        else if (i < 73728)   { W = Wc; Bh = chh; Bl = cll; K = 128; N = 40;  Np = 64;  j = i - 65536; }
        else return;
        int n = j / K, k = j % K;
        float v = (n < N) ? W[(long)k * N + n] : 0.f;
        unsigned short hh = f2bf(v);
        unsigned short ll = f2bf(v - bf2f(hh));
        long di = (((long)(k >> 5) * 4 + ((k >> 3) & 3)) * Np + n) * 8 + (k & 7);
        Bh[di] = hh;
        Bl[di] = ll;
        return;
    }
    // ---- A-split: rb-th 64-row block of n_feats -> nfh/nfl planes (NK=8)
    // streaming: no LDS, no barriers, all 1024 threads active.
    const int rb   = blockIdx.x - (NRG * CHP + 72);
    const int k4   = t & 3;
    const int row  = (t >> 2) & 63;
    const int tq   = t >> 8;                 // 0..3
    const int grow = rb * 64 + row;
    const float* rp = &nf[(long)grow * F];
#pragma unroll
    for (int hh2 = 0; hh2 < 2; hh2++) {
        const int tt = tq * 2 + hh2;         // k-step 0..7
        float4 v0 = make_float4(0.f, 0.f, 0.f, 0.f);
        float4 v1 = make_float4(0.f, 0.f, 0.f, 0.f);
        if (grow < NN) {
            v0 = *(const float4*)&rp[tt * 32 + k4 * 8];
            v1 = *(const float4*)&rp[tt * 32 + k4 * 8 + 4];
        }
        unsigned short a0 = f2bf(v0.x), a1 = f2bf(v0.y), a2 = f2bf(v0.z), a3 = f2bf(v0.w);
        unsigned short a4 = f2bf(v1.x), a5 = f2bf(v1.y), a6 = f2bf(v1.z), a7 = f2bf(v1.w);
        unsigned short b0 = f2bf(v0.x - bf2f(a0)), b1 = f2bf(v0.y - bf2f(a1));
        unsigned short b2 = f2bf(v0.z - bf2f(a2)), b3 = f2bf(v0.w - bf2f(a3));
        unsigned short b4 = f2bf(v1.x - bf2f(a4)), b5 = f2bf(v1.y - bf2f(a5));
        unsigned short b6 = f2bf(v1.z - bf2f(a6)), b7 = f2bf(v1.w - bf2f(a7));
        uint4 hv, lv;
        hv.x = (unsigned)a0 | ((unsigned)a1 << 16);
        hv.y = (unsigned)a2 | ((unsigned)a3 << 16);
        hv.z = (unsigned)a4 | ((unsigned)a5 << 16);
        hv.w = (unsigned)a6 | ((unsigned)a7 << 16);
        lv.x = (unsigned)b0 | ((unsigned)b1 << 16);
        lv.y = (unsigned)b2 | ((unsigned)b3 << 16);
        lv.z = (unsigned)b4 | ((unsigned)b5 << 16);
        lv.w = (unsigned)b6 | ((unsigned)b7 << 16);
        const long base = ((((long)rb * 8 + tt) * 4 + k4) * 64 + row) * 8;
        *(uint4*)&nfh[base] = hv;
        *(uint4*)&nfl[base] = lv;
    }
}

// ------------------------------------------------ D2: merge_scan (196) + proj GEMM (782)
__global__ __launch_bounds__(256) void merge_proj(
        const unsigned short* __restrict__ p_out, unsigned short* __restrict__ p_in,
        int* __restrict__ cnt_in, float* __restrict__ rs_out, float* __restrict__ rs_in,
        int* __restrict__ row_start, int* __restrict__ block_sums, int n, int nb,
        const unsigned short* __restrict__ Ah, const unsigned short* __restrict__ Al,
        const unsigned short* __restrict__ Bh, const unsigned short* __restrict__ Bl,
        const float* __restrict__ bias,
        unsigned short* __restrict__ xh, unsigned short* __restrict__ xl, int M) {
    if ((int)blockIdx.x < nb) {
        __shared__ int sh[256];
        const int t = threadIdx.x;
        const int i = blockIdx.x * 256 + t;
        int si = 0;
        if (i < n) {
            const int r = i / RSZ, off = i % RSZ;
            const long pb = (long)r * CHP * RSZ + off;
            int so = 0;
#pragma unroll 8
            for (int b = 0; b < CHP; b++) {
                so += p_out[pb + (long)b * RSZ];
                int v = p_in[pb + (long)b * RSZ];
                p_in[pb + (long)b * RSZ] = (unsigned short)si;
                si += v;
            }
            cnt_in[i] = si;
            rs_out[i] = rsqrtf((float)max(so, 1));
            rs_in[i]  = rsqrtf((float)max(si, 1));
        }
        sh[t] = si;
        __syncthreads();
#pragma unroll
        for (int off = 1; off < 256; off <<= 1) {
            int u = (t >= off) ? sh[t - off] : 0;
            __syncthreads();
            sh[t] += u;
            __syncthreads();
        }
        if (i < n) row_start[i] = sh[t] - si;
        if (t == 255) block_sums[blockIdx.x] = sh[255];
        return;
    }
    gemm_body<2, 128, 8>(blockIdx.x - nb, Ah, Al, Bh, Bl, bias, nullptr,
                         xh, xl, M, 128);
}

// ------------------------------------------------ D3: scan_sums (1) + layer1 GEMM (782)
__global__ __launch_bounds__(256) void scansums_gemm(
        int* __restrict__ block_sums, int nb,
        const unsigned short* __restrict__ Ah, const unsigned short* __restrict__ Al,
        const unsigned short* __restrict__ Bh, const unsigned short* __restrict__ Bl,
        const float* __restrict__ row_scale, unsigned short* __restrict__ outh, int M) {
    if (blockIdx.x == 0) {
        __shared__ int sh[256];
        const int t = threadIdx.x;
        const int v = (t < nb) ? block_sums[t] : 0;
        sh[t] = v;
        __syncthreads();
#pragma unroll
        for (int off = 1; off < 256; off <<= 1) {
            int u = (t >= off) ? sh[t - off] : 0;
            __syncthreads();
            sh[t] += u;
            __syncthreads();
        }
        if (t < nb) block_sums[t] = sh[t] - v;
        return;
    }
    gemm_body<1, 128, 4>(blockIdx.x - 1, Ah, Al, Bh, Bl, nullptr, row_scale,
                         outh, nullptr, M, 128);
}

// ------------------------------------------------ D4: CSR fill, 1024 threads
__global__ __launch_bounds__(1024) void fill_csr_part(
        const int* __restrict__ src, const int* __restrict__ dst,
        const int* __restrict__ row_start, const int* __restrict__ block_sums,
        const unsigned short* __restrict__ p_in,
        int* __restrict__ csr_src, int E, int n_nodes) {
    __shared__ int cur[RSZ];
    const int r = blockIdx.x;
    const int b = blockIdx.y;
    const int base = r * RSZ;
    const long po = ((long)r * CHP + b) * RSZ;
    for (int i = threadIdx.x; i < RSZ; i += 1024) {
        int node = base + i;
        int rs = (node < n_nodes) ? (row_start[node] + block_sums[node >> 8]) : 0;
        cur[i] = rs + (int)p_in[po + i];
    }
    __syncthreads();
    const int CE = (E + CHP - 1) / CHP;
    const int e0 = b * CE, e1 = min(E, e0 + CE);
#pragma unroll 8
    for (int e = e0 + threadIdx.x; e < e1; e += 1024) {
        int d = dst[e];
        unsigned dof = (unsigned)(d - base);
        if (dof < (unsigned)RSZ) {
            int pos = atomicAdd(&cur[dof], 1);   // LDS atomic
            csr_src[pos] = src[e];
        }
    }
}

// ---------------------------------------------------------------- fused aggregate+GEMM
// Block = 16 nodes (NN = 3125*16, no tail). Phase 1: per-wave gather/reduce (4
// nodes/wave, same wave count & pattern as the old 12500-block aggregate), land
// hi/lo split rows in row-major padded LDS [16][136] (stride 272B: write slots
// (l+sl)%8, read slots (lr+quad+4t)%8 -- both bank-optimal). Phase 2: 16xBN GEMM
// K=128, A from LDS, B (weight planes) from L2. Numerics identical to the old
// split-plane path (same split values, same 3-product order, same epilogue).
// CMODE 1: oh[gr*128+gc] = bf16(acc*rs_out[gr])   (layer-2, W2)
// CMODE 0: outf[gr*40+gc] = acc + bias2[gc]       (classifier, Wc)
template<int CMODE>
__global__ __launch_bounds__(256) void agg_gemm(
        const uint4* __restrict__ h4, const int* __restrict__ csr_src,
        const int* __restrict__ row_start, const int* __restrict__ block_sums,
        const int* __restrict__ cnt_in, const float* __restrict__ rs_in,
        const float* __restrict__ abias,
        const unsigned short* __restrict__ Bh, const unsigned short* __restrict__ Bl,
        const float* __restrict__ rs_out, const float* __restrict__ bias2,
        unsigned short* __restrict__ oh, float* __restrict__ outf) {
    constexpr int BN = (CMODE == 1) ? 128 : 64;
    constexpr int NT = BN / 64;
    constexpr int NP = (CMODE == 1) ? 128 : 64;
    __shared__ unsigned short Ash[16 * 136];
    __shared__ unsigned short Asl[16 * 136];

    const int tid  = threadIdx.x;
    const int wave = tid >> 6;
    const int lane = tid & 63;
    const int grp  = lane >> 4;        // 0..3 = neighbor slot
    const int sl   = lane & 15;        // uint4 index in row

    // ---- phase 1: aggregate (4 nodes per wave, interleaved local rows)
    for (int j = 0; j < 4; j++) {
        const int l = j * 4 + wave;              // local row 0..15
        const int v = blockIdx.x * 16 + l;       // always < NN (3125*16)
        const int s0  = row_start[v] + block_sums[v >> 8];
        const int cnt = cnt_in[v];

        float ax0 = 0.f, ay0 = 0.f, ax1 = 0.f, ay1 = 0.f;
        float ax2 = 0.f, ay2 = 0.f, ax3 = 0.f, ay3 = 0.f;
        int i0 = 0;
        for (; i0 + 8 <= cnt; i0 += 8) {         // 8 neighbors in flight
            int sA = csr_src[s0 + i0 + grp];
            int sB = csr_src[s0 + i0 + 4 + grp];
            uint4 uA = h4[(long)sA * 16 + sl];
            uint4 uB = h4[(long)sB * 16 + sl];
            ax0 += __uint_as_float(uA.x << 16) + __uint_as_float(uB.x << 16);
            ay0 += __uint_as_float(uA.x & 0xffff0000u) + __uint_as_float(uB.x & 0xffff0000u);
            ax1 += __uint_as_float(uA.y << 16) + __uint_as_float(uB.y << 16);
            ay1 += __uint_as_float(uA.y & 0xffff0000u) + __uint_as_float(uB.y & 0xffff0000u);
            ax2 += __uint_as_float(uA.z << 16) + __uint_as_float(uB.z << 16);
            ay2 += __uint_as_float(uA.z & 0xffff0000u) + __uint_as_float(uB.z & 0xffff0000u);
            ax3 += __uint_as_float(uA.w << 16) + __uint_as_float(uB.w << 16);
            ay3 += __uint_as_float(uA.w & 0xffff0000u) + __uint_as_float(uB.w & 0xffff0000u);
        }
        for (; i0 + 4 <= cnt; i0 += 4) {
            int s = csr_src[s0 + i0 + grp];
            uint4 u = h4[(long)s * 16 + sl];
            ax0 += __uint_as_float(u.x << 16); ay0 += __uint_as_float(u.x & 0xffff0000u);
            ax1 += __uint_as_float(u.y << 16); ay1 += __uint_as_float(u.y & 0xffff0000u);
            ax2 += __uint_as_float(u.z << 16); ay2 += __uint_as_float(u.z & 0xffff0000u);
            ax3 += __uint_as_float(u.w << 16); ay3 += __uint_as_float(u.w & 0xffff0000u);
        }
        if (i0 + grp < cnt) {                    // 0..3 tail neighbors
            int s = csr_src[s0 + i0 + grp];
            uint4 u = h4[(long)s * 16 + sl];
            ax0 += __uint_as_float(u.x << 16); ay0 += __uint_as_float(u.x & 0xffff0000u);
            ax1 += __uint_as_float(u.y << 16); ay1 += __uint_as_float(u.y & 0xffff0000u);
            ax2 += __uint_as_float(u.z << 16); ay2 += __uint_as_float(u.z & 0xffff0000u);
            ax3 += __uint_as_float(u.w << 16); ay3 += __uint_as_float(u.w & 0xffff0000u);
        }
        // sum across the 4 lane-groups (bits 4,5 of lane)
        ax0 += __shfl_xor(ax0, 16); ay0 += __shfl_xor(ay0, 16);
        ax1 += __shfl_xor(ax1, 16); ay1 += __shfl_xor(ay1, 16);
        ax2 += __shfl_xor(ax2, 16); ay2 += __shfl_xor(ay2, 16);
        ax3 += __shfl_xor(ax3, 16); ay3 += __shfl_xor(ay3, 16);
        ax0 += __shfl_xor(ax0, 32); ay0 += __shfl_xor(ay0, 32);
        ax1 += __shfl_xor(ax1, 32); ay1 += __shfl_xor(ay1, 32);
        ax2 += __shfl_xor(ax2, 32); ay2 += __shfl_xor(ay2, 32);
        ax3 += __shfl_xor(ax3, 32); ay3 += __shfl_xor(ay3, 32);

        if (grp == 0) {                          // lanes 0..15: cols sl*8..sl*8+7
            const float rs = rs_in[v];
            const float2 b0 = ((const float2*)abias)[sl * 4 + 0];
            const float2 b1 = ((const float2*)abias)[sl * 4 + 1];
            const float2 b2 = ((const float2*)abias)[sl * 4 + 2];
            const float2 b3 = ((const float2*)abias)[sl * 4 + 3];
            float w0 = fmaxf(ax0 * rs + b0.x, 0.f), w1 = fmaxf(ay0 * rs + b0.y, 0.f);
            float w2 = fmaxf(ax1 * rs + b1.x, 0.f), w3 = fmaxf(ay1 * rs + b1.y, 0.f);
            float w4 = fmaxf(ax2 * rs + b2.x, 0.f), w5 = fmaxf(ay2 * rs + b2.y, 0.f);
            float w6 = fmaxf(ax3 * rs + b3.x, 0.f), w7 = fmaxf(ay3 * rs + b3.y, 0.f);
            unsigned short h0 = f2bf(w0), h1 = f2bf(w1), h2 = f2bf(w2), h3 = f2bf(w3);
            unsigned short h4v = f2bf(w4), h5 = f2bf(w5), h6 = f2bf(w6), h7 = f2bf(w7);
            uint4 hv, lv;
            hv.x = (unsigned)h0 | ((unsigned)h1 << 16);
            hv.y = (unsigned)h2 | ((unsigned)h3 << 16);
            hv.z = (unsigned)h4v | ((unsigned)h5 << 16);
            hv.w = (unsigned)h6 | ((unsigned)h7 << 16);
            unsigned short l0 = f2bf(w0 - bf2f(h0)), l1 = f2bf(w1 - bf2f(h1));
            unsigned short l2 = f2bf(w2 - bf2f(h2)), l3 = f2bf(w3 - bf2f(h3));
            unsigned short l4 = f2bf(w4 - bf2f(h4v)), l5 = f2bf(w5 - bf2f(h5));
            unsigned short l6 = f2bf(w6 - bf2f(h6)), l7 = f2bf(w7 - bf2f(h7));
            lv.x = (unsigned)l0 | ((unsigned)l1 << 16);
            lv.y = (unsigned)l2 | ((unsigned)l3 << 16);
            lv.z = (unsigned)l4 | ((unsigned)l5 << 16);
            lv.w = (unsigned)l6 | ((unsigned)l7 << 16);
            *(uint4*)&Ash[l * 136 + sl * 8] = hv;
            *(uint4*)&Asl[l * 136 + sl * 8] = lv;
        }
    }
    __syncthreads();

    // ---- phase 2: GEMM 16 x BN, K=128; A from LDS, B planes from L2
    const int quad = grp;
    const int lr   = sl;
    const int wn0  = wave * (BN / 4);
    f32x4 acc[NT];
#pragma unroll
    for (int nt = 0; nt < NT; nt++) acc[nt] = (f32x4){0.f, 0.f, 0.f, 0.f};

#pragma unroll
    for (int t = 0; t < 4; t++) {
        bf16x8 ah = *(const bf16x8*)&Ash[lr * 136 + t * 32 + quad * 8];
        bf16x8 av = *(const bf16x8*)&Asl[lr * 136 + t * 32 + quad * 8];
        bf16x8 bh[NT], bv[NT];
#pragma unroll
        for (int nt = 0; nt < NT; nt++) {
            long off = ((long)(t * 4 + quad) * NP + wn0 + nt * 16 + lr) * 8;
            bh[nt] = *(const bf16x8*)&Bh[off];
            bv[nt] = *(const bf16x8*)&Bl[off];
        }
#pragma unroll
        for (int nt = 0; nt < NT; nt++) {
            acc[nt] = __builtin_amdgcn_mfma_f32_16x16x32_bf16(ah, bh[nt], acc[nt], 0, 0, 0);
            acc[nt] = __builtin_amdgcn_mfma_f32_16x16x32_bf16(av, bh[nt], acc[nt], 0, 0, 0);
            acc[nt] = __builtin_amdgcn_mfma_f32_16x16x32_bf16(ah, bv[nt], acc[nt], 0, 0, 0);
        }
    }

#pragma unroll
    for (int nt = 0; nt < NT; nt++) {
        const int gc = wn0 + nt * 16 + lr;
#pragma unroll
        for (int r = 0; r < 4; r++) {
            const int gr = blockIdx.x * 16 + quad * 4 + r;
            if (CMODE == 1) {
                oh[(long)gr * 128 + gc] = f2bf(acc[nt][r] * rs_out[gr]);
            } else {
                if (gc < C) outf[(long)gr * C + gc] = acc[nt][r] + bias2[gc];
            }
        }
    }
}

// ---------------------------------------------------------------- launch
extern "C" void kernel_launch(void* const* d_in, const int* in_sizes, int n_in,
                              void* d_out, int out_size, void* d_ws, size_t ws_size,
                              hipStream_t stream) {
    const float* n_feats = (const float*)d_in[0];
    const int*   src     = (const int*)d_in[1];
    const int*   dst     = (const int*)d_in[2];
    const float* Wp      = (const float*)d_in[3];
    const float* bp      = (const float*)d_in[4];
    const float* W1      = (const float*)d_in[5];
    const float* b1      = (const float*)d_in[6];
    const float* W2      = (const float*)d_in[7];
    const float* b2      = (const float*)d_in[8];
    const float* Wc      = (const float*)d_in[9];
    const float* bc      = (const float*)d_in[10];
    float* out = (float*)d_out;
    const int E = in_sizes[1];

    const long PSZ = (long)NRG * CHP * RSZ;    // partials: 1,638,400 u16 (3.28 MB)
    const long XPL = (long)GBK * 4 * 2048;     // x-plane elems (K=128 layout)
    const long NPL = (long)GBK * 8 * 2048;     // n_feats-plane elems (K=256 layout)

    // workspace layout (~115 MB of 256 MiB)
    char* ws = (char*)d_ws;
    unsigned short* hbuf  = (unsigned short*)ws;                    // NN*H bf16
    unsigned short* xh    = hbuf + (long)NN * H;                    // XPL
    unsigned short* xl    = xh + XPL;
    unsigned short* nfh   = xl + XPL;                               // NPL
    unsigned short* nfl   = nfh + NPL;
    unsigned short* bt_ph = nfl + NPL;                              // 8*4*128*8
    unsigned short* bt_pl = bt_ph + 32768;
    unsigned short* bt_1h = bt_pl + 32768;                          // 4*4*128*8
    unsigned short* bt_1l = bt_1h + 16384;
    unsigned short* bt_2h = bt_1l + 16384;
    unsigned short* bt_2l = bt_2h + 16384;
    unsigned short* bt_ch = bt_2l + 16384;                          // 4*4*64*8
    unsigned short* bt_cl = bt_ch + 8192;
    int*   cnt_in     = (int*)(bt_cl + 8192);                       // N
    int*   row_start  = cnt_in + NN;                                // N (within-block excl)
    float* rs_out     = (float*)(row_start + NN);                   // N
    float* rs_in      = rs_out + NN;                                // N
    int*   block_sums = (int*)(rs_in + NN);                         // 256
    unsigned short* p_out = (unsigned short*)(block_sums + 256);    // PSZ u16
    unsigned short* p_in  = p_out + PSZ;                            // PSZ u16
    int*   csr_src    = (int*)(p_in + PSZ);                         // E
    unsigned short* hbuf2 = (unsigned short*)(csr_src + E);         // NN*H bf16

    const int NB = (NN + 255) / 256;    // 196
    const int AB = NN / 16;             // 3125 fused agg+GEMM blocks

    // D1: histograms (256, XCD-pinned) + weight prep (72) + n_feats split (782)
    hist_prep<<<NRG * CHP + 72 + GBK, 1024, 0, stream>>>(
        src, dst, p_out, p_in, E, Wp, W1, W2, Wc,
        bt_ph, bt_pl, bt_1h, bt_1l, bt_2h, bt_2l, bt_ch, bt_cl,
        n_feats, nfh, nfl);
    // D2: merge+scan (196) + proj GEMM (782): xh/xl = split(n_feats @ Wp + bp)
    merge_proj<<<NB + GBK, 256, 0, stream>>>(
        p_out, p_in, cnt_in, rs_out, rs_in, row_start, block_sums, NN, NB,
        nfh, nfl, bt_ph, bt_pl, bp, xh, xl, NN);
    // D3: scan of block sums (1) + layer-1 GEMM (782): hbuf = bf16((x@W1)*rs_out)
    scansums_gemm<<<1 + GBK, 256, 0, stream>>>(
        block_sums, NB, xh, xl, bt_1h, bt_1l, rs_out, hbuf, NN);
    // D4: CSR fill (no global atomics), 1024 threads
    fill_csr_part<<<dim3(NRG, CHP), 1024, 0, stream>>>(
        src, dst, row_start, block_sums, p_in, csr_src, E, NN);
    // D5: fused aggregate-1 + layer-2 GEMM: hbuf2 = bf16((relu(rs_in*(A hbuf)+b1) @ W2)*rs_out)
    agg_gemm<1><<<AB, 256, 0, stream>>>(
        (const uint4*)hbuf, csr_src, row_start, block_sums, cnt_in, rs_in, b1,
        bt_2h, bt_2l, rs_out, nullptr, hbuf2, nullptr);
    // D6: fused aggregate-2 + classifier: out = relu(rs_in*(A hbuf2)+b2) @ Wc + bc
    agg_gemm<0><<<AB, 256, 0, stream>>>(
        (const uint4*)hbuf2, csr_src, row_start, block_sums, cnt_in, rs_in, b2,
        bt_ch, bt_cl, nullptr, bc, nullptr, out);
}